// Round 13
// baseline (192.378 us; speedup 1.0000x reference)
//
#include <hip/hip_runtime.h>

// Problem constants: B=2, T=2048, C=1024, H=16, HS=64. fp32 I/O, bf16 internal.
#define TB 2
#define TT 2048
#define TC 1024
#define TH 16
#define THS 64

typedef short bf16x8 __attribute__((ext_vector_type(8)));
typedef float f32x4 __attribute__((ext_vector_type(4)));

// Q pre-scale: (1/sqrt(C)) * log2(e), folded into Qb at QKV-GEMM epilogue
#define QSCALE 0.0450842200278f

// round-to-nearest-even fp32 -> bf16 bit pattern (manual; used in cold kernels)
__device__ inline unsigned short f2b(float f) {
    unsigned u = __builtin_bit_cast(unsigned, f);
    unsigned r = (u + 0x7fffu + ((u >> 16) & 1u)) >> 16;
    return (unsigned short)r;
}
// native RNE fp32->bf16 via compiler fptrunc (lowers to HW cvt on gfx950).
__device__ inline unsigned short f2b_hw(float f) {
    __bf16 h = (__bf16)f;
    return __builtin_bit_cast(unsigned short, h);
}
__device__ inline float b2f(unsigned short h) {
    unsigned u = ((unsigned)h) << 16;
    return __builtin_bit_cast(float, u);
}

// async global->LDS 16B/lane. LDS dest contract: wave-uniform base + lane*16.
__device__ inline void gl_lds16(const unsigned short* g, unsigned short* l) {
    __builtin_amdgcn_global_load_lds(
        (const __attribute__((address_space(1))) unsigned int*)(g),
        (__attribute__((address_space(3))) unsigned int*)(l), 16, 0, 0);
}

// 16-lane all-reduce sum via DPP row_ror butterfly (once per row at kernel end)
__device__ inline float dpp_sum16(float x) {
    int t;
    t = __builtin_amdgcn_update_dpp(0, __builtin_bit_cast(int, x), 0x128, 0xf, 0xf, true);
    x += __builtin_bit_cast(float, t);
    t = __builtin_amdgcn_update_dpp(0, __builtin_bit_cast(int, x), 0x124, 0xf, 0xf, true);
    x += __builtin_bit_cast(float, t);
    t = __builtin_amdgcn_update_dpp(0, __builtin_bit_cast(int, x), 0x122, 0xf, 0xf, true);
    x += __builtin_bit_cast(float, t);
    t = __builtin_amdgcn_update_dpp(0, __builtin_bit_cast(int, x), 0x121, 0xf, 0xf, true);
    x += __builtin_bit_cast(float, t);
    return x;
}

// ---------------- convert fp32 -> bf16, 8 elements/thread ----------------
__global__ void cvt_bf16_k(const float* __restrict__ in, unsigned short* __restrict__ out) {
    const int i = blockIdx.x * blockDim.x + threadIdx.x;
    const float4* p = (const float4*)in + (size_t)i * 2;
    const float4 a = p[0], b = p[1];
    bf16x8 v;
    v[0] = (short)f2b(a.x); v[1] = (short)f2b(a.y);
    v[2] = (short)f2b(a.z); v[3] = (short)f2b(a.w);
    v[4] = (short)f2b(b.x); v[5] = (short)f2b(b.y);
    v[6] = (short)f2b(b.z); v[7] = (short)f2b(b.w);
    *(bf16x8*)(out + (size_t)i * 8) = v;
}

// ------------- transpose + convert: fp32 in[R][Cc] -> bf16 out[Cc][R] -------------
__global__ void transpose_cvt_k(const float* __restrict__ in,
                                unsigned short* __restrict__ out, int R, int Cc) {
    __shared__ float tile[32][33];
    const int tx = threadIdx.x, ty = threadIdx.y;
    const int r0 = blockIdx.y * 32, c0 = blockIdx.x * 32;
#pragma unroll
    for (int i = 0; i < 4; i++)
        tile[ty + i * 8][tx] = in[(size_t)(r0 + ty + i * 8) * Cc + c0 + tx];
    __syncthreads();
#pragma unroll
    for (int i = 0; i < 4; i++)
        out[(size_t)(c0 + ty + i * 8) * R + r0 + tx] = f2b(tile[tx][ty + i * 8]);
}

// ------ V transpose: Vb[bh][t][d] -> Vt[bh][d][t], bf16, coalesced both sides ----
__global__ void vt_k(const unsigned short* __restrict__ Vb,
                     unsigned short* __restrict__ Vt) {
    __shared__ unsigned short tile[32][33];
    const int tx = threadIdx.x, ty = threadIdx.y;
    const int d0 = blockIdx.x * 32, t0 = blockIdx.y * 32, bh = blockIdx.z;
    const unsigned short* src = Vb + (size_t)bh * TT * THS;
    unsigned short* dst = Vt + (size_t)bh * THS * TT;
#pragma unroll
    for (int i = 0; i < 4; i++)
        tile[ty + i * 8][tx] = src[(size_t)(t0 + ty + i * 8) * THS + d0 + tx];
    __syncthreads();
#pragma unroll
    for (int i = 0; i < 4; i++)
        dst[(size_t)(d0 + ty + i * 8) * TT + t0 + tx] = tile[tx][ty + i * 8];
}

// ------- QKV GEMM: C = Xb * Wq_t^T, scatter epilogue -> K/Q/V [B,H,T,64] ---------
__global__ __launch_bounds__(256) void gemm_qkv(
    const unsigned short* __restrict__ A, const unsigned short* __restrict__ Bt, int K,
    unsigned short* __restrict__ outK, unsigned short* __restrict__ outQ,
    unsigned short* __restrict__ outV) {
    __shared__ __align__(16) unsigned short As[128 * 32];
    __shared__ __align__(16) unsigned short Bs[128 * 32];

    const int tid = threadIdx.x;
    const int wave = tid >> 6, lane = tid & 63;
    const int quad = lane >> 4, l16 = lane & 15;
    const int wm = (wave >> 1) * 64, wn = (wave & 1) * 64;
    const int m0 = blockIdx.y * 128, n0 = blockIdx.x * 128;

    const f32x4 vzero = {0.f, 0.f, 0.f, 0.f};
    f32x4 acc[4][4];
#pragma unroll
    for (int i = 0; i < 4; i++)
#pragma unroll
        for (int j = 0; j < 4; j++) acc[i][j] = vzero;

    const int nk = K >> 5;
    for (int kt = 0; kt < nk; ++kt) {
        const int k0 = kt * 32;
        __syncthreads();
#pragma unroll
        for (int it = 0; it < 2; ++it) {
            const int chunk = tid + it * 256;
            const int r = chunk >> 2, col = (chunk & 3) * 8;
            gl_lds16(A + (size_t)(m0 + r) * K + k0 + col, &As[chunk * 8]);
            gl_lds16(Bt + (size_t)(n0 + r) * K + k0 + col, &Bs[chunk * 8]);
        }
        __syncthreads();
        bf16x8 af[4], bfr[4];
#pragma unroll
        for (int f = 0; f < 4; ++f) {
            af[f] = *(const bf16x8*)(&As[(wm + f * 16 + l16) * 32 + quad * 8]);
            bfr[f] = *(const bf16x8*)(&Bs[(wn + f * 16 + l16) * 32 + quad * 8]);
        }
#pragma unroll
        for (int fm = 0; fm < 4; ++fm)
#pragma unroll
            for (int fn = 0; fn < 4; ++fn)
                acc[fm][fn] = __builtin_amdgcn_mfma_f32_16x16x32_bf16(
                    af[fm], bfr[fn], acc[fm][fn], 0, 0, 0);
    }

    // epilogue: C/D layout col=lane&15, row=quad*4+reg
#pragma unroll
    for (int fm = 0; fm < 4; ++fm) {
#pragma unroll
        for (int fn = 0; fn < 4; ++fn) {
#pragma unroll
            for (int r = 0; r < 4; ++r) {
                const int row = m0 + wm + fm * 16 + quad * 4 + r;
                const int col = n0 + wn + fn * 16 + l16;
                const float val = acc[fm][fn][r];
                const int b = row >> 11, t = row & (TT - 1);
                const int chunkc = col >> 10, cc = col & (TC - 1);
                const int hh = cc >> 6, d = cc & 63;
                const size_t idx = (size_t)((b * TH + hh) * TT + t) * THS + d;
                if (chunkc == 0)
                    outK[idx] = f2b(val);  // module split order: K first!
                else if (chunkc == 1)
                    outQ[idx] = f2b(val * QSCALE);  // pre-scaled Q
                else
                    outV[idx] = f2b(val);  // coalesced; vt_k transposes after
            }
        }
    }
}

// ------- proj GEMM: out[M,N] = A[M,K] * Bt[N,K]^T, 128x64 tile, fp32 out ---------
__global__ __launch_bounds__(256) void gemm_proj(
    const unsigned short* __restrict__ A, const unsigned short* __restrict__ Bt,
    int M, int N, int K, float* __restrict__ outF) {
    __shared__ __align__(16) unsigned short As[128 * 32];
    __shared__ __align__(16) unsigned short Bs[64 * 32];

    const int tid = threadIdx.x;
    const int wave = tid >> 6, lane = tid & 63;
    const int quad = lane >> 4, l16 = lane & 15;
    const int wm = wave * 32;
    const int m0 = blockIdx.y * 128, n0 = blockIdx.x * 64;

    const f32x4 vzero = {0.f, 0.f, 0.f, 0.f};
    f32x4 acc[2][4];
#pragma unroll
    for (int i = 0; i < 2; i++)
#pragma unroll
        for (int j = 0; j < 4; j++) acc[i][j] = vzero;

    const int nk = K >> 5;
    for (int kt = 0; kt < nk; ++kt) {
        const int k0 = kt * 32;
        __syncthreads();
#pragma unroll
        for (int it = 0; it < 2; ++it) {
            const int chunk = tid + it * 256;
            const int r = chunk >> 2, col = (chunk & 3) * 8;
            gl_lds16(A + (size_t)(m0 + r) * K + k0 + col, &As[chunk * 8]);
        }
        {
            const int r = tid >> 2, col = (tid & 3) * 8;
            gl_lds16(Bt + (size_t)(n0 + r) * K + k0 + col, &Bs[tid * 8]);
        }
        __syncthreads();
        bf16x8 af[2], bfr[4];
#pragma unroll
        for (int f = 0; f < 2; ++f)
            af[f] = *(const bf16x8*)(&As[(wm + f * 16 + l16) * 32 + quad * 8]);
#pragma unroll
        for (int f = 0; f < 4; ++f)
            bfr[f] = *(const bf16x8*)(&Bs[(f * 16 + l16) * 32 + quad * 8]);
#pragma unroll
        for (int fm = 0; fm < 2; ++fm)
#pragma unroll
            for (int fn = 0; fn < 4; ++fn)
                acc[fm][fn] = __builtin_amdgcn_mfma_f32_16x16x32_bf16(
                    af[fm], bfr[fn], acc[fm][fn], 0, 0, 0);
    }

#pragma unroll
    for (int fm = 0; fm < 2; ++fm)
#pragma unroll
        for (int fn = 0; fn < 4; ++fn)
#pragma unroll
            for (int r = 0; r < 4; ++r) {
                const int row = m0 + wm + fm * 16 + quad * 4 + r;
                const int col = n0 + fn * 16 + l16;
                outF[(size_t)row * N + col] = acc[fm][fn][r];
            }
}

// ---- flash attention v4: 8 waves x 16 q-rows, LDS K/V, counted-vmcnt pipeline ----
// Best harness-verified config (R8: total 190.7us, attn 49.2us). 8 waves x 16
// rows (512 threads), 128 rows/block; 3 K/V LDS buffers; stage kt+2 each iter
// (2 gl_lds16/wave); raw s_barrier with counted s_waitcnt vmcnt(2).
__global__ __launch_bounds__(512) void attn_k(
    const unsigned short* __restrict__ Qb, const unsigned short* __restrict__ Kb,
    const unsigned short* __restrict__ Vt, unsigned short* __restrict__ AO) {
    __shared__ __align__(16) unsigned short Ks[3][64 * 64];  // [t'][d], swizzled
    __shared__ __align__(16) unsigned short Vs[3][64 * 64];  // [d][t'], swizzled
    __shared__ __align__(16) unsigned short U[8][1152];      // per-wave P staging

    const int tid = threadIdx.x;
    const int w = tid >> 6, lane = tid & 63;
    const int quad = lane >> 4, l16 = lane & 15;
    const int bh = blockIdx.x;  // 0..31 fastest: spreads heads across XCDs
    const int y = blockIdx.y;
    const int qb = (y < 8) ? 15 - y : y - 8;  // balanced pairs: (15-y) + y = 15
    const int q0w = qb * 128 + w * 16;        // this wave's 16 q-rows
    const unsigned short* Qh = Qb + (size_t)bh * TT * THS;
    const unsigned short* Kh = Kb + (size_t)bh * TT * THS;
    const unsigned short* Vh = Vt + (size_t)bh * THS * TT;
    const int b = bh >> 4, h = bh & 15;

    bf16x8 aQ[2];
#pragma unroll
    for (int ks = 0; ks < 2; ++ks)
        aQ[ks] = *(const bf16x8*)(
            Qh + (size_t)(q0w + l16) * THS + ks * 32 + quad * 8);

    const float NEGINF = -__builtin_inff();
    const f32x4 vzero = {0.f, 0.f, 0.f, 0.f};
    f32x4 o[4];
    float lp[4];
#pragma unroll
    for (int i = 0; i < 4; i++) { o[i] = vzero; lp[i] = 0.f; }

    const int nkt = 2 * qb + 2;  // 64-key tiles covering [0, qb*128+128); >= 2

    // stage tile kt_ into buffer bf: 512 threads cover 512 16B-chunks in one pass.
    // chunk c: row=c>>3; LDS chunk c&7 holds global chunk (c&7)^(row&7) (G21).
    auto stage = [&](int kt_, int bf) {
        const int c = tid;
        const int row = c >> 3, g = (c & 7) ^ (row & 7);
        gl_lds16(Kh + (size_t)(kt_ * 64 + row) * THS + g * 8, &Ks[bf][c * 8]);
        gl_lds16(Vh + (size_t)row * TT + kt_ * 64 + g * 8, &Vs[bf][c * 8]);
    };

    // ---- prologue: stage tiles 0 and 1; wait only for tile 0 (vmcnt(2)) ----
    stage(0, 0);
    stage(1, 1);
    asm volatile("s_waitcnt vmcnt(2)" ::: "memory");
    __builtin_amdgcn_s_barrier();

    int cur = 0;
    for (int kt = 0; kt < nkt; ++kt) {
        const int t0 = kt * 64;
        const bool st = (kt + 2 < nkt);
        // stage kt+2 into buffer (kt+2)%3 == (cur+2)%3
        if (st) {
            const int bf = (cur >= 1) ? cur - 1 : cur + 2;  // (cur+2)%3
            stage(kt + 2, bf);
        }
        // ---- compute (wave-uniform guard; no barriers inside) ----
        if (t0 <= q0w + 15) {
            const unsigned short* Kc = &Ks[cur][0];
            const unsigned short* Vc = &Vs[cur][0];
            bf16x8 bK[8];
#pragma unroll
            for (int nt = 0; nt < 4; ++nt)
#pragma unroll
                for (int ks = 0; ks < 2; ++ks) {
                    const int row = nt * 16 + l16;
                    bK[nt * 2 + ks] = *(const bf16x8*)(
                        Kc + row * 64 + (((ks * 4 + quad) ^ (row & 7)) * 8));
                }
            const bool needmask = (t0 + 63 > q0w);
            f32x4 s[4];
#pragma unroll
            for (int nt = 0; nt < 4; ++nt) s[nt] = vzero;
#pragma unroll
            for (int ks = 0; ks < 2; ++ks)
#pragma unroll
                for (int nt = 0; nt < 4; ++nt)
                    s[nt] = __builtin_amdgcn_mfma_f32_16x16x32_bf16(
                        aQ[ks], bK[nt * 2 + ks], s[nt], 0, 0, 0);
            unsigned short* Pw = &U[w][0];  // 16 rows x stride 72
#pragma unroll
            for (int r = 0; r < 4; ++r) {
                const int row = q0w + quad * 4 + r;
                float v0 = s[0][r], v1 = s[1][r], v2 = s[2][r], v3 = s[3][r];
                if (needmask) {
                    if (t0 + l16 > row) v0 = NEGINF;
                    if (t0 + 16 + l16 > row) v1 = NEGINF;
                    if (t0 + 32 + l16 > row) v2 = NEGINF;
                    if (t0 + 48 + l16 > row) v3 = NEGINF;
                }
                const float p0 = __builtin_amdgcn_exp2f(v0);
                const float p1 = __builtin_amdgcn_exp2f(v1);
                const float p2 = __builtin_amdgcn_exp2f(v2);
                const float p3 = __builtin_amdgcn_exp2f(v3);
                lp[r] += (p0 + p1) + (p2 + p3);
                const int pr = (quad * 4 + r) * 72;
                Pw[pr + l16] = f2b_hw(p0);
                Pw[pr + 16 + l16] = f2b_hw(p1);
                Pw[pr + 32 + l16] = f2b_hw(p2);
                Pw[pr + 48 + l16] = f2b_hw(p3);
            }
            asm volatile("s_waitcnt lgkmcnt(0)" ::: "memory");  // per-wave P visibility
            bf16x8 aP[2];
            aP[0] = *(const bf16x8*)(Pw + l16 * 72 + quad * 8);
            aP[1] = *(const bf16x8*)(Pw + l16 * 72 + 32 + quad * 8);
            bf16x8 bV[8];
#pragma unroll
            for (int nt = 0; nt < 4; ++nt)
#pragma unroll
                for (int ks = 0; ks < 2; ++ks) {
                    const int row = nt * 16 + l16;
                    bV[nt * 2 + ks] = *(const bf16x8*)(
                        Vc + row * 64 + (((ks * 4 + quad) ^ (row & 7)) * 8));
                }
#pragma unroll
            for (int ks = 0; ks < 2; ++ks)
#pragma unroll
                for (int nt = 0; nt < 4; ++nt)
                    o[nt] = __builtin_amdgcn_mfma_f32_16x16x32_bf16(
                        aP[ks], bV[nt * 2 + ks], o[nt], 0, 0, 0);
        }
        // counted drain: complete all staging issued BEFORE this iteration; this
        // iteration's 2 (if any) stay in flight across the barrier (T4).
        if (st)
            asm volatile("s_waitcnt vmcnt(2)" ::: "memory");
        else
            asm volatile("s_waitcnt vmcnt(0)" ::: "memory");
        __builtin_amdgcn_s_barrier();
        cur = (cur == 2) ? 0 : cur + 1;
    }

    // ---- epilogue: per-wave l reduce + direct scaled AO write (no merge) ----
#pragma unroll
    for (int r = 0; r < 4; ++r) {
        const float L = dpp_sum16(lp[r]);
        const float rcpL = __builtin_amdgcn_rcpf(L);
        const int t = q0w + quad * 4 + r;
        unsigned short* dst = AO + ((size_t)(b * TT + t)) * TC + h * 64;
#pragma unroll
        for (int nt = 0; nt < 4; ++nt)
            dst[nt * 16 + l16] = f2b_hw(o[nt][r] * rcpL);
    }
}

extern "C" void kernel_launch(void* const* d_in, const int* in_sizes, int n_in,
                              void* d_out, int out_size, void* d_ws, size_t ws_size,
                              hipStream_t stream) {
    const float* X = (const float*)d_in[0];      // [2,2048,1024] fp32
    const float* Wqkv = (const float*)d_in[1];   // [1024,3072] fp32
    const float* Wproj = (const float*)d_in[2];  // [1024,1024] fp32
    float* out = (float*)d_out;                  // [2,2048,1024] fp32

    unsigned short* ws = (unsigned short*)d_ws;
    unsigned short* Xb = ws;                           // [4096,1024] bf16
    unsigned short* Wq_t = Xb + 4096 * 1024;           // [3072,1024] bf16
    unsigned short* Wp_t = Wq_t + 3072 * 1024;         // [1024,1024] bf16
    unsigned short* Qb = Wp_t + 1024 * 1024;           // [B,H,T,64] (pre-scaled)
    unsigned short* Kb = Qb + TB * TH * TT * THS;      // [B,H,T,64]
    unsigned short* Vb = Kb + TB * TH * TT * THS;      // [B,H,T,64] (pre-transpose)
    unsigned short* Vt = Vb + TB * TH * TT * THS;      // [B,H,64,T]
    unsigned short* AO = Vt + TB * TH * TT * THS;      // [B,T,C] bf16

    cvt_bf16_k<<<dim3((4096 * 1024) / (8 * 256)), 256, 0, stream>>>(X, Xb);
    transpose_cvt_k<<<dim3(3072 / 32, 1024 / 32), dim3(32, 8), 0, stream>>>(Wqkv, Wq_t, 1024, 3072);
    transpose_cvt_k<<<dim3(1024 / 32, 1024 / 32), dim3(32, 8), 0, stream>>>(Wproj, Wp_t, 1024, 1024);
    gemm_qkv<<<dim3(3072 / 128, 4096 / 128), 256, 0, stream>>>(Xb, Wq_t, 1024, Kb, Qb, Vb);
    vt_k<<<dim3(THS / 32, TT / 32, TB * TH), dim3(32, 8), 0, stream>>>(Vb, Vt);
    attn_k<<<dim3(32, 16), 512, 0, stream>>>(Qb, Kb, Vt, AO);
    gemm_proj<<<dim3(1024 / 64, 4096 / 128), 256, 0, stream>>>(
        AO, Wp_t, 4096, 1024, 1024, out);
}

// Round 14
// 191.621 us; speedup vs baseline: 1.0040x; 1.0040x over previous
//
#include <hip/hip_runtime.h>

// Problem constants: B=2, T=2048, C=1024, H=16, HS=64. fp32 I/O, bf16 internal.
#define TB 2
#define TT 2048
#define TC 1024
#define TH 16
#define THS 64

typedef short bf16x8 __attribute__((ext_vector_type(8)));
typedef float f32x4 __attribute__((ext_vector_type(4)));

// Q pre-scale: (1/sqrt(C)) * log2(e), folded into Qb at QKV-GEMM epilogue
#define QSCALE 0.0450842200278f

// round-to-nearest-even fp32 -> bf16 bit pattern (manual; used in cold kernels)
__device__ inline unsigned short f2b(float f) {
    unsigned u = __builtin_bit_cast(unsigned, f);
    unsigned r = (u + 0x7fffu + ((u >> 16) & 1u)) >> 16;
    return (unsigned short)r;
}
// native RNE fp32->bf16 via compiler fptrunc (lowers to HW cvt on gfx950).
__device__ inline unsigned short f2b_hw(float f) {
    __bf16 h = (__bf16)f;
    return __builtin_bit_cast(unsigned short, h);
}
__device__ inline float b2f(unsigned short h) {
    unsigned u = ((unsigned)h) << 16;
    return __builtin_bit_cast(float, u);
}

// async global->LDS 16B/lane. LDS dest contract: wave-uniform base + lane*16.
__device__ inline void gl_lds16(const unsigned short* g, unsigned short* l) {
    __builtin_amdgcn_global_load_lds(
        (const __attribute__((address_space(1))) unsigned int*)(g),
        (__attribute__((address_space(3))) unsigned int*)(l), 16, 0, 0);
}

// 16-lane all-reduce sum via DPP row_ror butterfly (once per row at kernel end)
__device__ inline float dpp_sum16(float x) {
    int t;
    t = __builtin_amdgcn_update_dpp(0, __builtin_bit_cast(int, x), 0x128, 0xf, 0xf, true);
    x += __builtin_bit_cast(float, t);
    t = __builtin_amdgcn_update_dpp(0, __builtin_bit_cast(int, x), 0x124, 0xf, 0xf, true);
    x += __builtin_bit_cast(float, t);
    t = __builtin_amdgcn_update_dpp(0, __builtin_bit_cast(int, x), 0x122, 0xf, 0xf, true);
    x += __builtin_bit_cast(float, t);
    t = __builtin_amdgcn_update_dpp(0, __builtin_bit_cast(int, x), 0x121, 0xf, 0xf, true);
    x += __builtin_bit_cast(float, t);
    return x;
}

// ---------------- convert fp32 -> bf16, 8 elements/thread ----------------
__global__ void cvt_bf16_k(const float* __restrict__ in, unsigned short* __restrict__ out) {
    const int i = blockIdx.x * blockDim.x + threadIdx.x;
    const float4* p = (const float4*)in + (size_t)i * 2;
    const float4 a = p[0], b = p[1];
    bf16x8 v;
    v[0] = (short)f2b(a.x); v[1] = (short)f2b(a.y);
    v[2] = (short)f2b(a.z); v[3] = (short)f2b(a.w);
    v[4] = (short)f2b(b.x); v[5] = (short)f2b(b.y);
    v[6] = (short)f2b(b.z); v[7] = (short)f2b(b.w);
    *(bf16x8*)(out + (size_t)i * 8) = v;
}

// ------------- transpose + convert: fp32 in[R][Cc] -> bf16 out[Cc][R] -------------
__global__ void transpose_cvt_k(const float* __restrict__ in,
                                unsigned short* __restrict__ out, int R, int Cc) {
    __shared__ float tile[32][33];
    const int tx = threadIdx.x, ty = threadIdx.y;
    const int r0 = blockIdx.y * 32, c0 = blockIdx.x * 32;
#pragma unroll
    for (int i = 0; i < 4; i++)
        tile[ty + i * 8][tx] = in[(size_t)(r0 + ty + i * 8) * Cc + c0 + tx];
    __syncthreads();
#pragma unroll
    for (int i = 0; i < 4; i++)
        out[(size_t)(c0 + ty + i * 8) * R + r0 + tx] = f2b(tile[tx][ty + i * 8]);
}

// ------ V transpose: Vb[bh][t][d] -> Vt[bh][d][t], bf16, coalesced both sides ----
__global__ void vt_k(const unsigned short* __restrict__ Vb,
                     unsigned short* __restrict__ Vt) {
    __shared__ unsigned short tile[32][33];
    const int tx = threadIdx.x, ty = threadIdx.y;
    const int d0 = blockIdx.x * 32, t0 = blockIdx.y * 32, bh = blockIdx.z;
    const unsigned short* src = Vb + (size_t)bh * TT * THS;
    unsigned short* dst = Vt + (size_t)bh * THS * TT;
#pragma unroll
    for (int i = 0; i < 4; i++)
        tile[ty + i * 8][tx] = src[(size_t)(t0 + ty + i * 8) * THS + d0 + tx];
    __syncthreads();
#pragma unroll
    for (int i = 0; i < 4; i++)
        dst[(size_t)(d0 + ty + i * 8) * TT + t0 + tx] = tile[tx][ty + i * 8];
}

// ------- QKV GEMM: C = Xb * Wq_t^T, scatter epilogue -> K/Q/V [B,H,T,64] ---------
// R14: epilogue rewritten with wave-uniform hoisting. chunkc (K/Q/V select), hh,
// b, tbase are all functions of the 64-aligned bases (n0+wn, m0+wm) -> scalar.
// Old epilogue: ~20 VALU/element x 192 (div/branch/64-bit idx) ~ 2x the main
// loop. New: scalar base + {mul, cvt, store imm-offset} per element (~4x cut).
// Also: bijective XCD swizzle (768 blocks = 8 x 96) -> each XCD owns 4 contiguous
// grid rows -> A-panel stays in its 4MB L2 (T1).
__global__ __launch_bounds__(256) void gemm_qkv(
    const unsigned short* __restrict__ A, const unsigned short* __restrict__ Bt, int K,
    unsigned short* __restrict__ outK, unsigned short* __restrict__ outQ,
    unsigned short* __restrict__ outV) {
    __shared__ __align__(16) unsigned short As[128 * 32];
    __shared__ __align__(16) unsigned short Bs[128 * 32];

    const int tid = threadIdx.x;
    const int wave = tid >> 6, lane = tid & 63;
    const int quad = lane >> 4, l16 = lane & 15;
    const int wm = (wave >> 1) * 64, wn = (wave & 1) * 64;
    // XCD-aware bijective remap: hw id -> tile id so ids on one XCD (id%8) get
    // 96 contiguous tiles (= 4 full rows of the 24-wide grid).
    const int hwid = blockIdx.y * 24 + blockIdx.x;
    const int swid = (hwid & 7) * 96 + (hwid >> 3);
    const int m0 = (swid / 24) * 128, n0 = (swid % 24) * 128;

    const f32x4 vzero = {0.f, 0.f, 0.f, 0.f};
    f32x4 acc[4][4];
#pragma unroll
    for (int i = 0; i < 4; i++)
#pragma unroll
        for (int j = 0; j < 4; j++) acc[i][j] = vzero;

    const int nk = K >> 5;
    for (int kt = 0; kt < nk; ++kt) {
        const int k0 = kt * 32;
        __syncthreads();
#pragma unroll
        for (int it = 0; it < 2; ++it) {
            const int chunk = tid + it * 256;
            const int r = chunk >> 2, col = (chunk & 3) * 8;
            gl_lds16(A + (size_t)(m0 + r) * K + k0 + col, &As[chunk * 8]);
            gl_lds16(Bt + (size_t)(n0 + r) * K + k0 + col, &Bs[chunk * 8]);
        }
        __syncthreads();
        bf16x8 af[4], bfr[4];
#pragma unroll
        for (int f = 0; f < 4; ++f) {
            af[f] = *(const bf16x8*)(&As[(wm + f * 16 + l16) * 32 + quad * 8]);
            bfr[f] = *(const bf16x8*)(&Bs[(wn + f * 16 + l16) * 32 + quad * 8]);
        }
#pragma unroll
        for (int fm = 0; fm < 4; ++fm)
#pragma unroll
            for (int fn = 0; fn < 4; ++fn)
                acc[fm][fn] = __builtin_amdgcn_mfma_f32_16x16x32_bf16(
                    af[fm], bfr[fn], acc[fm][fn], 0, 0, 0);
    }

    // ---- epilogue (C/D layout col=lane&15, row=quad*4+reg), hoisted scalar form.
    // col base cw = n0+wn is 64-aligned: a 64-wide range crosses no 1024- or
    // 64-boundary -> chunkc, hh wave-uniform. Row base rw = m0+wm is 64-aligned:
    // b, tbase wave-uniform. d = fn*16 + l16; t = tbase + fm*16 + quad*4 + r.
    {
        const int cw = n0 + wn;
        const int chunkc = cw >> 10;            // 0:K 1:Q 2:V (module split order)
        const int hh = (cw & (TC - 1)) >> 6;
        const int rw = m0 + wm;
        const int b = rw >> 11;
        const int tbase = rw & (TT - 1);
        unsigned short* outp = (chunkc == 0) ? outK : (chunkc == 1) ? outQ : outV;
        const float scale = (chunkc == 1) ? QSCALE : 1.0f;
        unsigned short* base =
            outp + ((size_t)((b * TH + hh) * TT + tbase)) * THS + l16;
#pragma unroll
        for (int fm = 0; fm < 4; ++fm) {
#pragma unroll
            for (int r = 0; r < 4; ++r) {
                unsigned short* rowp = base + (fm * 16 + quad * 4 + r) * THS;
#pragma unroll
                for (int fn = 0; fn < 4; ++fn)
                    rowp[fn * 16] = f2b_hw(acc[fm][fn][r] * scale);
            }
        }
    }
}

// ------- proj GEMM: out[M,N] = A[M,K] * Bt[N,K]^T, 128x64 tile, fp32 out ---------
__global__ __launch_bounds__(256) void gemm_proj(
    const unsigned short* __restrict__ A, const unsigned short* __restrict__ Bt,
    int M, int N, int K, float* __restrict__ outF) {
    __shared__ __align__(16) unsigned short As[128 * 32];
    __shared__ __align__(16) unsigned short Bs[64 * 32];

    const int tid = threadIdx.x;
    const int wave = tid >> 6, lane = tid & 63;
    const int quad = lane >> 4, l16 = lane & 15;
    const int wm = wave * 32;
    const int m0 = blockIdx.y * 128, n0 = blockIdx.x * 64;

    const f32x4 vzero = {0.f, 0.f, 0.f, 0.f};
    f32x4 acc[2][4];
#pragma unroll
    for (int i = 0; i < 2; i++)
#pragma unroll
        for (int j = 0; j < 4; j++) acc[i][j] = vzero;

    const int nk = K >> 5;
    for (int kt = 0; kt < nk; ++kt) {
        const int k0 = kt * 32;
        __syncthreads();
#pragma unroll
        for (int it = 0; it < 2; ++it) {
            const int chunk = tid + it * 256;
            const int r = chunk >> 2, col = (chunk & 3) * 8;
            gl_lds16(A + (size_t)(m0 + r) * K + k0 + col, &As[chunk * 8]);
        }
        {
            const int r = tid >> 2, col = (tid & 3) * 8;
            gl_lds16(Bt + (size_t)(n0 + r) * K + k0 + col, &Bs[tid * 8]);
        }
        __syncthreads();
        bf16x8 af[2], bfr[4];
#pragma unroll
        for (int f = 0; f < 2; ++f)
            af[f] = *(const bf16x8*)(&As[(wm + f * 16 + l16) * 32 + quad * 8]);
#pragma unroll
        for (int f = 0; f < 4; ++f)
            bfr[f] = *(const bf16x8*)(&Bs[(f * 16 + l16) * 32 + quad * 8]);
#pragma unroll
        for (int fm = 0; fm < 2; ++fm)
#pragma unroll
            for (int fn = 0; fn < 4; ++fn)
                acc[fm][fn] = __builtin_amdgcn_mfma_f32_16x16x32_bf16(
                    af[fm], bfr[fn], acc[fm][fn], 0, 0, 0);
    }

#pragma unroll
    for (int fm = 0; fm < 2; ++fm)
#pragma unroll
        for (int fn = 0; fn < 4; ++fn)
#pragma unroll
            for (int r = 0; r < 4; ++r) {
                const int row = m0 + wm + fm * 16 + quad * 4 + r;
                const int col = n0 + fn * 16 + l16;
                outF[(size_t)row * N + col] = acc[fm][fn][r];
            }
}

// ---- flash attention v4: 8 waves x 16 q-rows, LDS K/V, counted-vmcnt pipeline ----
// Best harness-verified config (R8/R13: attn 49.2-49.8us). 8 waves x 16 rows
// (512 threads), 128 rows/block; 3 K/V LDS buffers; stage kt+2 each iter
// (2 gl_lds16/wave); raw s_barrier with counted s_waitcnt vmcnt(2).
__global__ __launch_bounds__(512) void attn_k(
    const unsigned short* __restrict__ Qb, const unsigned short* __restrict__ Kb,
    const unsigned short* __restrict__ Vt, unsigned short* __restrict__ AO) {
    __shared__ __align__(16) unsigned short Ks[3][64 * 64];  // [t'][d], swizzled
    __shared__ __align__(16) unsigned short Vs[3][64 * 64];  // [d][t'], swizzled
    __shared__ __align__(16) unsigned short U[8][1152];      // per-wave P staging

    const int tid = threadIdx.x;
    const int w = tid >> 6, lane = tid & 63;
    const int quad = lane >> 4, l16 = lane & 15;
    const int bh = blockIdx.x;  // 0..31 fastest: spreads heads across XCDs
    const int y = blockIdx.y;
    const int qb = (y < 8) ? 15 - y : y - 8;  // balanced pairs: (15-y) + y = 15
    const int q0w = qb * 128 + w * 16;        // this wave's 16 q-rows
    const unsigned short* Qh = Qb + (size_t)bh * TT * THS;
    const unsigned short* Kh = Kb + (size_t)bh * TT * THS;
    const unsigned short* Vh = Vt + (size_t)bh * THS * TT;
    const int b = bh >> 4, h = bh & 15;

    bf16x8 aQ[2];
#pragma unroll
    for (int ks = 0; ks < 2; ++ks)
        aQ[ks] = *(const bf16x8*)(
            Qh + (size_t)(q0w + l16) * THS + ks * 32 + quad * 8);

    const float NEGINF = -__builtin_inff();
    const f32x4 vzero = {0.f, 0.f, 0.f, 0.f};
    f32x4 o[4];
    float lp[4];
#pragma unroll
    for (int i = 0; i < 4; i++) { o[i] = vzero; lp[i] = 0.f; }

    const int nkt = 2 * qb + 2;  // 64-key tiles covering [0, qb*128+128); >= 2

    // stage tile kt_ into buffer bf: 512 threads cover 512 16B-chunks in one pass.
    // chunk c: row=c>>3; LDS chunk c&7 holds global chunk (c&7)^(row&7) (G21).
    auto stage = [&](int kt_, int bf) {
        const int c = tid;
        const int row = c >> 3, g = (c & 7) ^ (row & 7);
        gl_lds16(Kh + (size_t)(kt_ * 64 + row) * THS + g * 8, &Ks[bf][c * 8]);
        gl_lds16(Vh + (size_t)row * TT + kt_ * 64 + g * 8, &Vs[bf][c * 8]);
    };

    // ---- prologue: stage tiles 0 and 1; wait only for tile 0 (vmcnt(2)) ----
    stage(0, 0);
    stage(1, 1);
    asm volatile("s_waitcnt vmcnt(2)" ::: "memory");
    __builtin_amdgcn_s_barrier();

    int cur = 0;
    for (int kt = 0; kt < nkt; ++kt) {
        const int t0 = kt * 64;
        const bool st = (kt + 2 < nkt);
        // stage kt+2 into buffer (kt+2)%3 == (cur+2)%3
        if (st) {
            const int bf = (cur >= 1) ? cur - 1 : cur + 2;  // (cur+2)%3
            stage(kt + 2, bf);
        }
        // ---- compute (wave-uniform guard; no barriers inside) ----
        if (t0 <= q0w + 15) {
            const unsigned short* Kc = &Ks[cur][0];
            const unsigned short* Vc = &Vs[cur][0];
            bf16x8 bK[8];
#pragma unroll
            for (int nt = 0; nt < 4; ++nt)
#pragma unroll
                for (int ks = 0; ks < 2; ++ks) {
                    const int row = nt * 16 + l16;
                    bK[nt * 2 + ks] = *(const bf16x8*)(
                        Kc + row * 64 + (((ks * 4 + quad) ^ (row & 7)) * 8));
                }
            const bool needmask = (t0 + 63 > q0w);
            f32x4 s[4];
#pragma unroll
            for (int nt = 0; nt < 4; ++nt) s[nt] = vzero;
#pragma unroll
            for (int ks = 0; ks < 2; ++ks)
#pragma unroll
                for (int nt = 0; nt < 4; ++nt)
                    s[nt] = __builtin_amdgcn_mfma_f32_16x16x32_bf16(
                        aQ[ks], bK[nt * 2 + ks], s[nt], 0, 0, 0);
            unsigned short* Pw = &U[w][0];  // 16 rows x stride 72
#pragma unroll
            for (int r = 0; r < 4; ++r) {
                const int row = q0w + quad * 4 + r;
                float v0 = s[0][r], v1 = s[1][r], v2 = s[2][r], v3 = s[3][r];
                if (needmask) {
                    if (t0 + l16 > row) v0 = NEGINF;
                    if (t0 + 16 + l16 > row) v1 = NEGINF;
                    if (t0 + 32 + l16 > row) v2 = NEGINF;
                    if (t0 + 48 + l16 > row) v3 = NEGINF;
                }
                const float p0 = __builtin_amdgcn_exp2f(v0);
                const float p1 = __builtin_amdgcn_exp2f(v1);
                const float p2 = __builtin_amdgcn_exp2f(v2);
                const float p3 = __builtin_amdgcn_exp2f(v3);
                lp[r] += (p0 + p1) + (p2 + p3);
                const int pr = (quad * 4 + r) * 72;
                Pw[pr + l16] = f2b_hw(p0);
                Pw[pr + 16 + l16] = f2b_hw(p1);
                Pw[pr + 32 + l16] = f2b_hw(p2);
                Pw[pr + 48 + l16] = f2b_hw(p3);
            }
            asm volatile("s_waitcnt lgkmcnt(0)" ::: "memory");  // per-wave P visibility
            bf16x8 aP[2];
            aP[0] = *(const bf16x8*)(Pw + l16 * 72 + quad * 8);
            aP[1] = *(const bf16x8*)(Pw + l16 * 72 + 32 + quad * 8);
            bf16x8 bV[8];
#pragma unroll
            for (int nt = 0; nt < 4; ++nt)
#pragma unroll
                for (int ks = 0; ks < 2; ++ks) {
                    const int row = nt * 16 + l16;
                    bV[nt * 2 + ks] = *(const bf16x8*)(
                        Vc + row * 64 + (((ks * 4 + quad) ^ (row & 7)) * 8));
                }
#pragma unroll
            for (int ks = 0; ks < 2; ++ks)
#pragma unroll
                for (int nt = 0; nt < 4; ++nt)
                    o[nt] = __builtin_amdgcn_mfma_f32_16x16x32_bf16(
                        aP[ks], bV[nt * 2 + ks], o[nt], 0, 0, 0);
        }
        // counted drain: complete all staging issued BEFORE this iteration; this
        // iteration's 2 (if any) stay in flight across the barrier (T4).
        if (st)
            asm volatile("s_waitcnt vmcnt(2)" ::: "memory");
        else
            asm volatile("s_waitcnt vmcnt(0)" ::: "memory");
        __builtin_amdgcn_s_barrier();
        cur = (cur == 2) ? 0 : cur + 1;
    }

    // ---- epilogue: per-wave l reduce + direct scaled AO write (no merge) ----
#pragma unroll
    for (int r = 0; r < 4; ++r) {
        const float L = dpp_sum16(lp[r]);
        const float rcpL = __builtin_amdgcn_rcpf(L);
        const int t = q0w + quad * 4 + r;
        unsigned short* dst = AO + ((size_t)(b * TT + t)) * TC + h * 64;
#pragma unroll
        for (int nt = 0; nt < 4; ++nt)
            dst[nt * 16 + l16] = f2b_hw(o[nt][r] * rcpL);
    }
}

extern "C" void kernel_launch(void* const* d_in, const int* in_sizes, int n_in,
                              void* d_out, int out_size, void* d_ws, size_t ws_size,
                              hipStream_t stream) {
    const float* X = (const float*)d_in[0];      // [2,2048,1024] fp32
    const float* Wqkv = (const float*)d_in[1];   // [1024,3072] fp32
    const float* Wproj = (const float*)d_in[2];  // [1024,1024] fp32
    float* out = (float*)d_out;                  // [2,2048,1024] fp32

    unsigned short* ws = (unsigned short*)d_ws;
    unsigned short* Xb = ws;                           // [4096,1024] bf16
    unsigned short* Wq_t = Xb + 4096 * 1024;           // [3072,1024] bf16
    unsigned short* Wp_t = Wq_t + 3072 * 1024;         // [1024,1024] bf16
    unsigned short* Qb = Wp_t + 1024 * 1024;           // [B,H,T,64] (pre-scaled)
    unsigned short* Kb = Qb + TB * TH * TT * THS;      // [B,H,T,64]
    unsigned short* Vb = Kb + TB * TH * TT * THS;      // [B,H,T,64] (pre-transpose)
    unsigned short* Vt = Vb + TB * TH * TT * THS;      // [B,H,64,T]
    unsigned short* AO = Vt + TB * TH * TT * THS;      // [B,T,C] bf16

    cvt_bf16_k<<<dim3((4096 * 1024) / (8 * 256)), 256, 0, stream>>>(X, Xb);
    transpose_cvt_k<<<dim3(3072 / 32, 1024 / 32), dim3(32, 8), 0, stream>>>(Wqkv, Wq_t, 1024, 3072);
    transpose_cvt_k<<<dim3(1024 / 32, 1024 / 32), dim3(32, 8), 0, stream>>>(Wproj, Wp_t, 1024, 1024);
    gemm_qkv<<<dim3(3072 / 128, 4096 / 128), 256, 0, stream>>>(Xb, Wq_t, 1024, Kb, Qb, Vb);
    vt_k<<<dim3(THS / 32, TT / 32, TB * TH), dim3(32, 8), 0, stream>>>(Vb, Vt);
    attn_k<<<dim3(32, 16), 512, 0, stream>>>(Qb, Kb, Vt, AO);
    gemm_proj<<<dim3(1024 / 64, 4096 / 128), 256, 0, stream>>>(
        AO, Wp_t, 4096, 1024, 1024, out);
}

// Round 15
// 189.550 us; speedup vs baseline: 1.0149x; 1.0109x over previous
//
#include <hip/hip_runtime.h>

// Problem constants: B=2, T=2048, C=1024, H=16, HS=64. fp32 I/O, bf16 internal.
#define TB 2
#define TT 2048
#define TC 1024
#define TH 16
#define THS 64

typedef short bf16x8 __attribute__((ext_vector_type(8)));
typedef float f32x4 __attribute__((ext_vector_type(4)));

// Q pre-scale: (1/sqrt(C)) * log2(e), folded into Qb at QKV-GEMM epilogue
#define QSCALE 0.0450842200278f

// round-to-nearest-even fp32 -> bf16 bit pattern (manual; used in cold kernels)
__device__ inline unsigned short f2b(float f) {
    unsigned u = __builtin_bit_cast(unsigned, f);
    unsigned r = (u + 0x7fffu + ((u >> 16) & 1u)) >> 16;
    return (unsigned short)r;
}
// native RNE fp32->bf16 via compiler fptrunc (lowers to HW cvt on gfx950).
__device__ inline unsigned short f2b_hw(float f) {
    __bf16 h = (__bf16)f;
    return __builtin_bit_cast(unsigned short, h);
}
__device__ inline float b2f(unsigned short h) {
    unsigned u = ((unsigned)h) << 16;
    return __builtin_bit_cast(float, u);
}

// async global->LDS 16B/lane. LDS dest contract: wave-uniform base + lane*16.
__device__ inline void gl_lds16(const unsigned short* g, unsigned short* l) {
    __builtin_amdgcn_global_load_lds(
        (const __attribute__((address_space(1))) unsigned int*)(g),
        (__attribute__((address_space(3))) unsigned int*)(l), 16, 0, 0);
}

// 16-lane all-reduce sum via DPP row_ror butterfly (once per row at kernel end)
__device__ inline float dpp_sum16(float x) {
    int t;
    t = __builtin_amdgcn_update_dpp(0, __builtin_bit_cast(int, x), 0x128, 0xf, 0xf, true);
    x += __builtin_bit_cast(float, t);
    t = __builtin_amdgcn_update_dpp(0, __builtin_bit_cast(int, x), 0x124, 0xf, 0xf, true);
    x += __builtin_bit_cast(float, t);
    t = __builtin_amdgcn_update_dpp(0, __builtin_bit_cast(int, x), 0x122, 0xf, 0xf, true);
    x += __builtin_bit_cast(float, t);
    t = __builtin_amdgcn_update_dpp(0, __builtin_bit_cast(int, x), 0x121, 0xf, 0xf, true);
    x += __builtin_bit_cast(float, t);
    return x;
}

// ---------------- convert fp32 -> bf16, 8 elements/thread ----------------
__global__ void cvt_bf16_k(const float* __restrict__ in, unsigned short* __restrict__ out) {
    const int i = blockIdx.x * blockDim.x + threadIdx.x;
    const float4* p = (const float4*)in + (size_t)i * 2;
    const float4 a = p[0], b = p[1];
    bf16x8 v;
    v[0] = (short)f2b(a.x); v[1] = (short)f2b(a.y);
    v[2] = (short)f2b(a.z); v[3] = (short)f2b(a.w);
    v[4] = (short)f2b(b.x); v[5] = (short)f2b(b.y);
    v[6] = (short)f2b(b.z); v[7] = (short)f2b(b.w);
    *(bf16x8*)(out + (size_t)i * 8) = v;
}

// ------------- transpose + convert: fp32 in[R][Cc] -> bf16 out[Cc][R] -------------
__global__ void transpose_cvt_k(const float* __restrict__ in,
                                unsigned short* __restrict__ out, int R, int Cc) {
    __shared__ float tile[32][33];
    const int tx = threadIdx.x, ty = threadIdx.y;
    const int r0 = blockIdx.y * 32, c0 = blockIdx.x * 32;
#pragma unroll
    for (int i = 0; i < 4; i++)
        tile[ty + i * 8][tx] = in[(size_t)(r0 + ty + i * 8) * Cc + c0 + tx];
    __syncthreads();
#pragma unroll
    for (int i = 0; i < 4; i++)
        out[(size_t)(c0 + ty + i * 8) * R + r0 + tx] = f2b(tile[tx][ty + i * 8]);
}

// ------ V transpose: Vb[bh][t][d] -> Vt[bh][d][t], bf16, coalesced both sides ----
__global__ void vt_k(const unsigned short* __restrict__ Vb,
                     unsigned short* __restrict__ Vt) {
    __shared__ unsigned short tile[32][33];
    const int tx = threadIdx.x, ty = threadIdx.y;
    const int d0 = blockIdx.x * 32, t0 = blockIdx.y * 32, bh = blockIdx.z;
    const unsigned short* src = Vb + (size_t)bh * TT * THS;
    unsigned short* dst = Vt + (size_t)bh * THS * TT;
#pragma unroll
    for (int i = 0; i < 4; i++)
        tile[ty + i * 8][tx] = src[(size_t)(t0 + ty + i * 8) * THS + d0 + tx];
    __syncthreads();
#pragma unroll
    for (int i = 0; i < 4; i++)
        dst[(size_t)(d0 + ty + i * 8) * TT + t0 + tx] = tile[tx][ty + i * 8];
}

// ------- QKV GEMM: C = Xb * Wq_t^T, scatter epilogue -> K/Q/V [B,H,T,64] ---------
// R15: K-loop restructured to the SAME 3-buffer counted-vmcnt pipeline proven in
// attn_k (R8): issue stage(kt+2) BEFORE compute of kt; bottom s_waitcnt vmcnt(4)
// (completes stage(kt+1) = next iter's input; this iter's 4 staging instrs stay
// in flight across the barrier). Old structure drained vmcnt(0) every K-step ->
// staging latency fully exposed. LDS 48 KB -> 3 blocks/CU.
// Epilogue: wave-uniform hoisted addressing (R14). XCD swizzle (R14).
__global__ __launch_bounds__(256) void gemm_qkv(
    const unsigned short* __restrict__ A, const unsigned short* __restrict__ Bt, int K,
    unsigned short* __restrict__ outK, unsigned short* __restrict__ outQ,
    unsigned short* __restrict__ outV) {
    __shared__ __align__(16) unsigned short As[3][128 * 32];
    __shared__ __align__(16) unsigned short Bs[3][128 * 32];

    const int tid = threadIdx.x;
    const int wave = tid >> 6, lane = tid & 63;
    const int quad = lane >> 4, l16 = lane & 15;
    const int wm = (wave >> 1) * 64, wn = (wave & 1) * 64;
    // XCD-aware bijective remap: hw id -> tile id so ids on one XCD (id%8) get
    // 96 contiguous tiles (= 4 full rows of the 24-wide grid).
    const int hwid = blockIdx.y * 24 + blockIdx.x;
    const int swid = (hwid & 7) * 96 + (hwid >> 3);
    const int m0 = (swid / 24) * 128, n0 = (swid % 24) * 128;

    const f32x4 vzero = {0.f, 0.f, 0.f, 0.f};
    f32x4 acc[4][4];
#pragma unroll
    for (int i = 0; i < 4; i++)
#pragma unroll
        for (int j = 0; j < 4; j++) acc[i][j] = vzero;

    const int nk = K >> 5;  // 32

    // stage K-tile kt_ into buffer bf: 4 gl_lds16/thread (A,B interleaved).
    auto stage = [&](int kt_, int bf) {
#pragma unroll
        for (int it = 0; it < 2; ++it) {
            const int chunk = tid + it * 256;
            const int r = chunk >> 2, col = (chunk & 3) * 8;
            gl_lds16(A + (size_t)(m0 + r) * K + kt_ * 32 + col, &As[bf][chunk * 8]);
            gl_lds16(Bt + (size_t)(n0 + r) * K + kt_ * 32 + col, &Bs[bf][chunk * 8]);
        }
    };

    // prologue: stage tiles 0,1; wait for tile 0 only (8 outstanding -> <=4)
    stage(0, 0);
    stage(1, 1);
    asm volatile("s_waitcnt vmcnt(4)" ::: "memory");
    __builtin_amdgcn_s_barrier();

    int cur = 0;
    for (int kt = 0; kt < nk; ++kt) {
        const bool st = (kt + 2 < nk);
        if (st) {
            const int bf = (cur >= 1) ? cur - 1 : cur + 2;  // (cur+2)%3
            stage(kt + 2, bf);
        }
        bf16x8 af[4], bfr[4];
#pragma unroll
        for (int f = 0; f < 4; ++f) {
            af[f] = *(const bf16x8*)(&As[cur][(wm + f * 16 + l16) * 32 + quad * 8]);
            bfr[f] = *(const bf16x8*)(&Bs[cur][(wn + f * 16 + l16) * 32 + quad * 8]);
        }
#pragma unroll
        for (int fm = 0; fm < 4; ++fm)
#pragma unroll
            for (int fn = 0; fn < 4; ++fn)
                acc[fm][fn] = __builtin_amdgcn_mfma_f32_16x16x32_bf16(
                    af[fm], bfr[fn], acc[fm][fn], 0, 0, 0);
        // counted drain: completes stage(kt+1); stage(kt+2)'s 4 stay in flight.
        if (st)
            asm volatile("s_waitcnt vmcnt(4)" ::: "memory");
        else
            asm volatile("s_waitcnt vmcnt(0)" ::: "memory");
        __builtin_amdgcn_s_barrier();
        cur = (cur == 2) ? 0 : cur + 1;
    }

    // ---- epilogue (C/D layout col=lane&15, row=quad*4+reg), hoisted scalar form.
    {
        const int cw = n0 + wn;
        const int chunkc = cw >> 10;            // 0:K 1:Q 2:V (module split order)
        const int hh = (cw & (TC - 1)) >> 6;
        const int rw = m0 + wm;
        const int b = rw >> 11;
        const int tbase = rw & (TT - 1);
        unsigned short* outp = (chunkc == 0) ? outK : (chunkc == 1) ? outQ : outV;
        const float scale = (chunkc == 1) ? QSCALE : 1.0f;
        unsigned short* base =
            outp + ((size_t)((b * TH + hh) * TT + tbase)) * THS + l16;
#pragma unroll
        for (int fm = 0; fm < 4; ++fm) {
#pragma unroll
            for (int r = 0; r < 4; ++r) {
                unsigned short* rowp = base + (fm * 16 + quad * 4 + r) * THS;
#pragma unroll
                for (int fn = 0; fn < 4; ++fn)
                    rowp[fn * 16] = f2b_hw(acc[fm][fn][r] * scale);
            }
        }
    }
}

// ------- proj GEMM: out[M,N] = A[M,K] * Bt[N,K]^T, 128x64 tile, fp32 out ---------
// R15: same 3-buffer counted-vmcnt pipeline (3 staging instrs/wave/tile ->
// vmcnt(3)). LDS 36 KB -> 4 blocks/CU.
__global__ __launch_bounds__(256) void gemm_proj(
    const unsigned short* __restrict__ A, const unsigned short* __restrict__ Bt,
    int M, int N, int K, float* __restrict__ outF) {
    __shared__ __align__(16) unsigned short As[3][128 * 32];
    __shared__ __align__(16) unsigned short Bs[3][64 * 32];

    const int tid = threadIdx.x;
    const int wave = tid >> 6, lane = tid & 63;
    const int quad = lane >> 4, l16 = lane & 15;
    const int wm = wave * 32;
    const int m0 = blockIdx.y * 128, n0 = blockIdx.x * 64;

    const f32x4 vzero = {0.f, 0.f, 0.f, 0.f};
    f32x4 acc[2][4];
#pragma unroll
    for (int i = 0; i < 2; i++)
#pragma unroll
        for (int j = 0; j < 4; j++) acc[i][j] = vzero;

    const int nk = K >> 5;  // 32

    // stage K-tile kt_ into buffer bf: 3 gl_lds16/thread (A,A,B).
    auto stage = [&](int kt_, int bf) {
#pragma unroll
        for (int it = 0; it < 2; ++it) {
            const int chunk = tid + it * 256;
            const int r = chunk >> 2, col = (chunk & 3) * 8;
            gl_lds16(A + (size_t)(m0 + r) * K + kt_ * 32 + col, &As[bf][chunk * 8]);
        }
        {
            const int r = tid >> 2, col = (tid & 3) * 8;
            gl_lds16(Bt + (size_t)(n0 + r) * K + kt_ * 32 + col, &Bs[bf][tid * 8]);
        }
    };

    // prologue: stage tiles 0,1; wait for tile 0 only (6 outstanding -> <=3)
    stage(0, 0);
    stage(1, 1);
    asm volatile("s_waitcnt vmcnt(3)" ::: "memory");
    __builtin_amdgcn_s_barrier();

    int cur = 0;
    for (int kt = 0; kt < nk; ++kt) {
        const bool st = (kt + 2 < nk);
        if (st) {
            const int bf = (cur >= 1) ? cur - 1 : cur + 2;  // (cur+2)%3
            stage(kt + 2, bf);
        }
        bf16x8 af[2], bfr[4];
#pragma unroll
        for (int f = 0; f < 2; ++f)
            af[f] = *(const bf16x8*)(&As[cur][(wm + f * 16 + l16) * 32 + quad * 8]);
#pragma unroll
        for (int f = 0; f < 4; ++f)
            bfr[f] = *(const bf16x8*)(&Bs[cur][(f * 16 + l16) * 32 + quad * 8]);
#pragma unroll
        for (int fm = 0; fm < 2; ++fm)
#pragma unroll
            for (int fn = 0; fn < 4; ++fn)
                acc[fm][fn] = __builtin_amdgcn_mfma_f32_16x16x32_bf16(
                    af[fm], bfr[fn], acc[fm][fn], 0, 0, 0);
        // counted drain: completes stage(kt+1); stage(kt+2)'s 3 stay in flight.
        if (st)
            asm volatile("s_waitcnt vmcnt(3)" ::: "memory");
        else
            asm volatile("s_waitcnt vmcnt(0)" ::: "memory");
        __builtin_amdgcn_s_barrier();
        cur = (cur == 2) ? 0 : cur + 1;
    }

#pragma unroll
    for (int fm = 0; fm < 2; ++fm)
#pragma unroll
        for (int fn = 0; fn < 4; ++fn)
#pragma unroll
            for (int r = 0; r < 4; ++r) {
                const int row = m0 + wm + fm * 16 + quad * 4 + r;
                const int col = n0 + fn * 16 + l16;
                outF[(size_t)row * N + col] = acc[fm][fn][r];
            }
}

// ---- flash attention v4: 8 waves x 16 q-rows, LDS K/V, counted-vmcnt pipeline ----
// Best harness-verified config (R8/R13/R14: attn 49us). Unchanged.
__global__ __launch_bounds__(512) void attn_k(
    const unsigned short* __restrict__ Qb, const unsigned short* __restrict__ Kb,
    const unsigned short* __restrict__ Vt, unsigned short* __restrict__ AO) {
    __shared__ __align__(16) unsigned short Ks[3][64 * 64];  // [t'][d], swizzled
    __shared__ __align__(16) unsigned short Vs[3][64 * 64];  // [d][t'], swizzled
    __shared__ __align__(16) unsigned short U[8][1152];      // per-wave P staging

    const int tid = threadIdx.x;
    const int w = tid >> 6, lane = tid & 63;
    const int quad = lane >> 4, l16 = lane & 15;
    const int bh = blockIdx.x;  // 0..31 fastest: spreads heads across XCDs
    const int y = blockIdx.y;
    const int qb = (y < 8) ? 15 - y : y - 8;  // balanced pairs: (15-y) + y = 15
    const int q0w = qb * 128 + w * 16;        // this wave's 16 q-rows
    const unsigned short* Qh = Qb + (size_t)bh * TT * THS;
    const unsigned short* Kh = Kb + (size_t)bh * TT * THS;
    const unsigned short* Vh = Vt + (size_t)bh * THS * TT;
    const int b = bh >> 4, h = bh & 15;

    bf16x8 aQ[2];
#pragma unroll
    for (int ks = 0; ks < 2; ++ks)
        aQ[ks] = *(const bf16x8*)(
            Qh + (size_t)(q0w + l16) * THS + ks * 32 + quad * 8);

    const float NEGINF = -__builtin_inff();
    const f32x4 vzero = {0.f, 0.f, 0.f, 0.f};
    f32x4 o[4];
    float lp[4];
#pragma unroll
    for (int i = 0; i < 4; i++) { o[i] = vzero; lp[i] = 0.f; }

    const int nkt = 2 * qb + 2;  // 64-key tiles covering [0, qb*128+128); >= 2

    // stage tile kt_ into buffer bf: 512 threads cover 512 16B-chunks in one pass.
    // chunk c: row=c>>3; LDS chunk c&7 holds global chunk (c&7)^(row&7) (G21).
    auto stage = [&](int kt_, int bf) {
        const int c = tid;
        const int row = c >> 3, g = (c & 7) ^ (row & 7);
        gl_lds16(Kh + (size_t)(kt_ * 64 + row) * THS + g * 8, &Ks[bf][c * 8]);
        gl_lds16(Vh + (size_t)row * TT + kt_ * 64 + g * 8, &Vs[bf][c * 8]);
    };

    // ---- prologue: stage tiles 0 and 1; wait only for tile 0 (vmcnt(2)) ----
    stage(0, 0);
    stage(1, 1);
    asm volatile("s_waitcnt vmcnt(2)" ::: "memory");
    __builtin_amdgcn_s_barrier();

    int cur = 0;
    for (int kt = 0; kt < nkt; ++kt) {
        const int t0 = kt * 64;
        const bool st = (kt + 2 < nkt);
        // stage kt+2 into buffer (kt+2)%3 == (cur+2)%3
        if (st) {
            const int bf = (cur >= 1) ? cur - 1 : cur + 2;  // (cur+2)%3
            stage(kt + 2, bf);
        }
        // ---- compute (wave-uniform guard; no barriers inside) ----
        if (t0 <= q0w + 15) {
            const unsigned short* Kc = &Ks[cur][0];
            const unsigned short* Vc = &Vs[cur][0];
            bf16x8 bK[8];
#pragma unroll
            for (int nt = 0; nt < 4; ++nt)
#pragma unroll
                for (int ks = 0; ks < 2; ++ks) {
                    const int row = nt * 16 + l16;
                    bK[nt * 2 + ks] = *(const bf16x8*)(
                        Kc + row * 64 + (((ks * 4 + quad) ^ (row & 7)) * 8));
                }
            const bool needmask = (t0 + 63 > q0w);
            f32x4 s[4];
#pragma unroll
            for (int nt = 0; nt < 4; ++nt) s[nt] = vzero;
#pragma unroll
            for (int ks = 0; ks < 2; ++ks)
#pragma unroll
                for (int nt = 0; nt < 4; ++nt)
                    s[nt] = __builtin_amdgcn_mfma_f32_16x16x32_bf16(
                        aQ[ks], bK[nt * 2 + ks], s[nt], 0, 0, 0);
            unsigned short* Pw = &U[w][0];  // 16 rows x stride 72
#pragma unroll
            for (int r = 0; r < 4; ++r) {
                const int row = q0w + quad * 4 + r;
                float v0 = s[0][r], v1 = s[1][r], v2 = s[2][r], v3 = s[3][r];
                if (needmask) {
                    if (t0 + l16 > row) v0 = NEGINF;
                    if (t0 + 16 + l16 > row) v1 = NEGINF;
                    if (t0 + 32 + l16 > row) v2 = NEGINF;
                    if (t0 + 48 + l16 > row) v3 = NEGINF;
                }
                const float p0 = __builtin_amdgcn_exp2f(v0);
                const float p1 = __builtin_amdgcn_exp2f(v1);
                const float p2 = __builtin_amdgcn_exp2f(v2);
                const float p3 = __builtin_amdgcn_exp2f(v3);
                lp[r] += (p0 + p1) + (p2 + p3);
                const int pr = (quad * 4 + r) * 72;
                Pw[pr + l16] = f2b_hw(p0);
                Pw[pr + 16 + l16] = f2b_hw(p1);
                Pw[pr + 32 + l16] = f2b_hw(p2);
                Pw[pr + 48 + l16] = f2b_hw(p3);
            }
            asm volatile("s_waitcnt lgkmcnt(0)" ::: "memory");  // per-wave P visibility
            bf16x8 aP[2];
            aP[0] = *(const bf16x8*)(Pw + l16 * 72 + quad * 8);
            aP[1] = *(const bf16x8*)(Pw + l16 * 72 + 32 + quad * 8);
            bf16x8 bV[8];
#pragma unroll
            for (int nt = 0; nt < 4; ++nt)
#pragma unroll
                for (int ks = 0; ks < 2; ++ks) {
                    const int row = nt * 16 + l16;
                    bV[nt * 2 + ks] = *(const bf16x8*)(
                        Vc + row * 64 + (((ks * 4 + quad) ^ (row & 7)) * 8));
                }
#pragma unroll
            for (int ks = 0; ks < 2; ++ks)
#pragma unroll
                for (int nt = 0; nt < 4; ++nt)
                    o[nt] = __builtin_amdgcn_mfma_f32_16x16x32_bf16(
                        aP[ks], bV[nt * 2 + ks], o[nt], 0, 0, 0);
        }
        // counted drain: complete all staging issued BEFORE this iteration; this
        // iteration's 2 (if any) stay in flight across the barrier (T4).
        if (st)
            asm volatile("s_waitcnt vmcnt(2)" ::: "memory");
        else
            asm volatile("s_waitcnt vmcnt(0)" ::: "memory");
        __builtin_amdgcn_s_barrier();
        cur = (cur == 2) ? 0 : cur + 1;
    }

    // ---- epilogue: per-wave l reduce + direct scaled AO write (no merge) ----
#pragma unroll
    for (int r = 0; r < 4; ++r) {
        const float L = dpp_sum16(lp[r]);
        const float rcpL = __builtin_amdgcn_rcpf(L);
        const int t = q0w + quad * 4 + r;
        unsigned short* dst = AO + ((size_t)(b * TT + t)) * TC + h * 64;
#pragma unroll
        for (int nt = 0; nt < 4; ++nt)
            dst[nt * 16 + l16] = f2b_hw(o[nt][r] * rcpL);
    }
}

extern "C" void kernel_launch(void* const* d_in, const int* in_sizes, int n_in,
                              void* d_out, int out_size, void* d_ws, size_t ws_size,
                              hipStream_t stream) {
    const float* X = (const float*)d_in[0];      // [2,2048,1024] fp32
    const float* Wqkv = (const float*)d_in[1];   // [1024,3072] fp32
    const float* Wproj = (const float*)d_in[2];  // [1024,1024] fp32
    float* out = (float*)d_out;                  // [2,2048,1024] fp32

    unsigned short* ws = (unsigned short*)d_ws;
    unsigned short* Xb = ws;                           // [4096,1024] bf16
    unsigned short* Wq_t = Xb + 4096 * 1024;           // [3072,1024] bf16
    unsigned short* Wp_t = Wq_t + 3072 * 1024;         // [1024,1024] bf16
    unsigned short* Qb = Wp_t + 1024 * 1024;           // [B,H,T,64] (pre-scaled)
    unsigned short* Kb = Qb + TB * TH * TT * THS;      // [B,H,T,64]
    unsigned short* Vb = Kb + TB * TH * TT * THS;      // [B,H,T,64] (pre-transpose)
    unsigned short* Vt = Vb + TB * TH * TT * THS;      // [B,H,64,T]
    unsigned short* AO = Vt + TB * TH * TT * THS;      // [B,T,C] bf16

    cvt_bf16_k<<<dim3((4096 * 1024) / (8 * 256)), 256, 0, stream>>>(X, Xb);
    transpose_cvt_k<<<dim3(3072 / 32, 1024 / 32), dim3(32, 8), 0, stream>>>(Wqkv, Wq_t, 1024, 3072);
    transpose_cvt_k<<<dim3(1024 / 32, 1024 / 32), dim3(32, 8), 0, stream>>>(Wproj, Wp_t, 1024, 1024);
    gemm_qkv<<<dim3(3072 / 128, 4096 / 128), 256, 0, stream>>>(Xb, Wq_t, 1024, Kb, Qb, Vb);
    vt_k<<<dim3(THS / 32, TT / 32, TB * TH), dim3(32, 8), 0, stream>>>(Vb, Vt);
    attn_k<<<dim3(32, 16), 512, 0, stream>>>(Qb, Kb, Vt, AO);
    gemm_proj<<<dim3(1024 / 64, 4096 / 128), 256, 0, stream>>>(
        AO, Wp_t, 4096, 1024, 1024, out);
}

// Round 16
// 188.929 us; speedup vs baseline: 1.0183x; 1.0033x over previous
//
#include <hip/hip_runtime.h>

// Problem constants: B=2, T=2048, C=1024, H=16, HS=64. fp32 I/O, bf16 internal.
#define TB 2
#define TT 2048
#define TC 1024
#define TH 16
#define THS 64

typedef short bf16x8 __attribute__((ext_vector_type(8)));
typedef float f32x4 __attribute__((ext_vector_type(4)));

// Q pre-scale: (1/sqrt(C)) * log2(e), folded into Qb at QKV-GEMM epilogue
#define QSCALE 0.0450842200278f

// round-to-nearest-even fp32 -> bf16 bit pattern (manual; used in cold kernels)
__device__ inline unsigned short f2b(float f) {
    unsigned u = __builtin_bit_cast(unsigned, f);
    unsigned r = (u + 0x7fffu + ((u >> 16) & 1u)) >> 16;
    return (unsigned short)r;
}
// native RNE fp32->bf16 via compiler fptrunc (lowers to HW cvt on gfx950).
__device__ inline unsigned short f2b_hw(float f) {
    __bf16 h = (__bf16)f;
    return __builtin_bit_cast(unsigned short, h);
}
__device__ inline float b2f(unsigned short h) {
    unsigned u = ((unsigned)h) << 16;
    return __builtin_bit_cast(float, u);
}

// async global->LDS 16B/lane. LDS dest contract: wave-uniform base + lane*16.
__device__ inline void gl_lds16(const unsigned short* g, unsigned short* l) {
    __builtin_amdgcn_global_load_lds(
        (const __attribute__((address_space(1))) unsigned int*)(g),
        (__attribute__((address_space(3))) unsigned int*)(l), 16, 0, 0);
}

// 16-lane all-reduce sum via DPP row_ror butterfly (once per row at kernel end)
__device__ inline float dpp_sum16(float x) {
    int t;
    t = __builtin_amdgcn_update_dpp(0, __builtin_bit_cast(int, x), 0x128, 0xf, 0xf, true);
    x += __builtin_bit_cast(float, t);
    t = __builtin_amdgcn_update_dpp(0, __builtin_bit_cast(int, x), 0x124, 0xf, 0xf, true);
    x += __builtin_bit_cast(float, t);
    t = __builtin_amdgcn_update_dpp(0, __builtin_bit_cast(int, x), 0x122, 0xf, 0xf, true);
    x += __builtin_bit_cast(float, t);
    t = __builtin_amdgcn_update_dpp(0, __builtin_bit_cast(int, x), 0x121, 0xf, 0xf, true);
    x += __builtin_bit_cast(float, t);
    return x;
}

// ---------------- convert fp32 -> bf16, 8 elements/thread ----------------
__global__ void cvt_bf16_k(const float* __restrict__ in, unsigned short* __restrict__ out) {
    const int i = blockIdx.x * blockDim.x + threadIdx.x;
    const float4* p = (const float4*)in + (size_t)i * 2;
    const float4 a = p[0], b = p[1];
    bf16x8 v;
    v[0] = (short)f2b(a.x); v[1] = (short)f2b(a.y);
    v[2] = (short)f2b(a.z); v[3] = (short)f2b(a.w);
    v[4] = (short)f2b(b.x); v[5] = (short)f2b(b.y);
    v[6] = (short)f2b(b.z); v[7] = (short)f2b(b.w);
    *(bf16x8*)(out + (size_t)i * 8) = v;
}

// ------------- transpose + convert: fp32 in[R][Cc] -> bf16 out[Cc][R] -------------
__global__ void transpose_cvt_k(const float* __restrict__ in,
                                unsigned short* __restrict__ out, int R, int Cc) {
    __shared__ float tile[32][33];
    const int tx = threadIdx.x, ty = threadIdx.y;
    const int r0 = blockIdx.y * 32, c0 = blockIdx.x * 32;
#pragma unroll
    for (int i = 0; i < 4; i++)
        tile[ty + i * 8][tx] = in[(size_t)(r0 + ty + i * 8) * Cc + c0 + tx];
    __syncthreads();
#pragma unroll
    for (int i = 0; i < 4; i++)
        out[(size_t)(c0 + ty + i * 8) * R + r0 + tx] = f2b(tile[tx][ty + i * 8]);
}

// ------ V transpose: Vb[bh][t][d] -> Vt[bh][d][t], bf16, coalesced both sides ----
__global__ void vt_k(const unsigned short* __restrict__ Vb,
                     unsigned short* __restrict__ Vt) {
    __shared__ unsigned short tile[32][33];
    const int tx = threadIdx.x, ty = threadIdx.y;
    const int d0 = blockIdx.x * 32, t0 = blockIdx.y * 32, bh = blockIdx.z;
    const unsigned short* src = Vb + (size_t)bh * TT * THS;
    unsigned short* dst = Vt + (size_t)bh * THS * TT;
#pragma unroll
    for (int i = 0; i < 4; i++)
        tile[ty + i * 8][tx] = src[(size_t)(t0 + ty + i * 8) * THS + d0 + tx];
    __syncthreads();
#pragma unroll
    for (int i = 0; i < 4; i++)
        dst[(size_t)(d0 + ty + i * 8) * TT + t0 + tx] = tile[tx][ty + i * 8];
}

// ------- QKV GEMM: C = Xb * Wq_t^T, scatter epilogue -> K/Q/V [B,H,T,64] ---------
// 3-buffer counted-vmcnt pipeline (R15) + hoisted scalar epilogue + XCD swizzle
// (R14) + T5 setprio around the MFMA cluster (R16: 3 independent blocks/CU give
// the CU scheduler role diversity to arbitrate).
__global__ __launch_bounds__(256) void gemm_qkv(
    const unsigned short* __restrict__ A, const unsigned short* __restrict__ Bt, int K,
    unsigned short* __restrict__ outK, unsigned short* __restrict__ outQ,
    unsigned short* __restrict__ outV) {
    __shared__ __align__(16) unsigned short As[3][128 * 32];
    __shared__ __align__(16) unsigned short Bs[3][128 * 32];

    const int tid = threadIdx.x;
    const int wave = tid >> 6, lane = tid & 63;
    const int quad = lane >> 4, l16 = lane & 15;
    const int wm = (wave >> 1) * 64, wn = (wave & 1) * 64;
    const int hwid = blockIdx.y * 24 + blockIdx.x;
    const int swid = (hwid & 7) * 96 + (hwid >> 3);
    const int m0 = (swid / 24) * 128, n0 = (swid % 24) * 128;

    const f32x4 vzero = {0.f, 0.f, 0.f, 0.f};
    f32x4 acc[4][4];
#pragma unroll
    for (int i = 0; i < 4; i++)
#pragma unroll
        for (int j = 0; j < 4; j++) acc[i][j] = vzero;

    const int nk = K >> 5;  // 32

    auto stage = [&](int kt_, int bf) {
#pragma unroll
        for (int it = 0; it < 2; ++it) {
            const int chunk = tid + it * 256;
            const int r = chunk >> 2, col = (chunk & 3) * 8;
            gl_lds16(A + (size_t)(m0 + r) * K + kt_ * 32 + col, &As[bf][chunk * 8]);
            gl_lds16(Bt + (size_t)(n0 + r) * K + kt_ * 32 + col, &Bs[bf][chunk * 8]);
        }
    };

    stage(0, 0);
    stage(1, 1);
    asm volatile("s_waitcnt vmcnt(4)" ::: "memory");
    __builtin_amdgcn_s_barrier();

    int cur = 0;
    for (int kt = 0; kt < nk; ++kt) {
        const bool st = (kt + 2 < nk);
        if (st) {
            const int bf = (cur >= 1) ? cur - 1 : cur + 2;  // (cur+2)%3
            stage(kt + 2, bf);
        }
        bf16x8 af[4], bfr[4];
#pragma unroll
        for (int f = 0; f < 4; ++f) {
            af[f] = *(const bf16x8*)(&As[cur][(wm + f * 16 + l16) * 32 + quad * 8]);
            bfr[f] = *(const bf16x8*)(&Bs[cur][(wn + f * 16 + l16) * 32 + quad * 8]);
        }
        __builtin_amdgcn_s_setprio(1);
#pragma unroll
        for (int fm = 0; fm < 4; ++fm)
#pragma unroll
            for (int fn = 0; fn < 4; ++fn)
                acc[fm][fn] = __builtin_amdgcn_mfma_f32_16x16x32_bf16(
                    af[fm], bfr[fn], acc[fm][fn], 0, 0, 0);
        __builtin_amdgcn_s_setprio(0);
        if (st)
            asm volatile("s_waitcnt vmcnt(4)" ::: "memory");
        else
            asm volatile("s_waitcnt vmcnt(0)" ::: "memory");
        __builtin_amdgcn_s_barrier();
        cur = (cur == 2) ? 0 : cur + 1;
    }

    // ---- epilogue (C/D layout col=lane&15, row=quad*4+reg), hoisted scalar form.
    {
        const int cw = n0 + wn;
        const int chunkc = cw >> 10;            // 0:K 1:Q 2:V (module split order)
        const int hh = (cw & (TC - 1)) >> 6;
        const int rw = m0 + wm;
        const int b = rw >> 11;
        const int tbase = rw & (TT - 1);
        unsigned short* outp = (chunkc == 0) ? outK : (chunkc == 1) ? outQ : outV;
        const float scale = (chunkc == 1) ? QSCALE : 1.0f;
        unsigned short* base =
            outp + ((size_t)((b * TH + hh) * TT + tbase)) * THS + l16;
#pragma unroll
        for (int fm = 0; fm < 4; ++fm) {
#pragma unroll
            for (int r = 0; r < 4; ++r) {
                unsigned short* rowp = base + (fm * 16 + quad * 4 + r) * THS;
#pragma unroll
                for (int fn = 0; fn < 4; ++fn)
                    rowp[fn * 16] = f2b_hw(acc[fm][fn][r] * scale);
            }
        }
    }
}

// ------- proj GEMM: out[M,N] = A[M,K] * Bt[N,K]^T, 128x64 tile, fp32 out ---------
// 3-buffer counted-vmcnt pipeline (R15) + T5 setprio (R16).
__global__ __launch_bounds__(256) void gemm_proj(
    const unsigned short* __restrict__ A, const unsigned short* __restrict__ Bt,
    int M, int N, int K, float* __restrict__ outF) {
    __shared__ __align__(16) unsigned short As[3][128 * 32];
    __shared__ __align__(16) unsigned short Bs[3][64 * 32];

    const int tid = threadIdx.x;
    const int wave = tid >> 6, lane = tid & 63;
    const int quad = lane >> 4, l16 = lane & 15;
    const int wm = wave * 32;
    const int m0 = blockIdx.y * 128, n0 = blockIdx.x * 64;

    const f32x4 vzero = {0.f, 0.f, 0.f, 0.f};
    f32x4 acc[2][4];
#pragma unroll
    for (int i = 0; i < 2; i++)
#pragma unroll
        for (int j = 0; j < 4; j++) acc[i][j] = vzero;

    const int nk = K >> 5;  // 32

    auto stage = [&](int kt_, int bf) {
#pragma unroll
        for (int it = 0; it < 2; ++it) {
            const int chunk = tid + it * 256;
            const int r = chunk >> 2, col = (chunk & 3) * 8;
            gl_lds16(A + (size_t)(m0 + r) * K + kt_ * 32 + col, &As[bf][chunk * 8]);
        }
        {
            const int r = tid >> 2, col = (tid & 3) * 8;
            gl_lds16(Bt + (size_t)(n0 + r) * K + kt_ * 32 + col, &Bs[bf][tid * 8]);
        }
    };

    stage(0, 0);
    stage(1, 1);
    asm volatile("s_waitcnt vmcnt(3)" ::: "memory");
    __builtin_amdgcn_s_barrier();

    int cur = 0;
    for (int kt = 0; kt < nk; ++kt) {
        const bool st = (kt + 2 < nk);
        if (st) {
            const int bf = (cur >= 1) ? cur - 1 : cur + 2;  // (cur+2)%3
            stage(kt + 2, bf);
        }
        bf16x8 af[2], bfr[4];
#pragma unroll
        for (int f = 0; f < 2; ++f)
            af[f] = *(const bf16x8*)(&As[cur][(wm + f * 16 + l16) * 32 + quad * 8]);
#pragma unroll
        for (int f = 0; f < 4; ++f)
            bfr[f] = *(const bf16x8*)(&Bs[cur][(f * 16 + l16) * 32 + quad * 8]);
        __builtin_amdgcn_s_setprio(1);
#pragma unroll
        for (int fm = 0; fm < 2; ++fm)
#pragma unroll
            for (int fn = 0; fn < 4; ++fn)
                acc[fm][fn] = __builtin_amdgcn_mfma_f32_16x16x32_bf16(
                    af[fm], bfr[fn], acc[fm][fn], 0, 0, 0);
        __builtin_amdgcn_s_setprio(0);
        if (st)
            asm volatile("s_waitcnt vmcnt(3)" ::: "memory");
        else
            asm volatile("s_waitcnt vmcnt(0)" ::: "memory");
        __builtin_amdgcn_s_barrier();
        cur = (cur == 2) ? 0 : cur + 1;
    }

#pragma unroll
    for (int fm = 0; fm < 2; ++fm)
#pragma unroll
        for (int fn = 0; fn < 4; ++fn)
#pragma unroll
            for (int r = 0; r < 4; ++r) {
                const int row = m0 + wm + fm * 16 + quad * 4 + r;
                const int col = n0 + fn * 16 + l16;
                outF[(size_t)row * N + col] = acc[fm][fn][r];
            }
}

// ---- flash attention v4: 8 waves x 16 q-rows, LDS K/V, counted-vmcnt pipeline ----
// Best verified config (R8/R13-R15: attn ~49us) + T5 setprio around both MFMA
// clusters (R16: 2 independent blocks/CU -> scheduler role diversity; m191
// measured +4-7% for attn in this regime).
__global__ __launch_bounds__(512) void attn_k(
    const unsigned short* __restrict__ Qb, const unsigned short* __restrict__ Kb,
    const unsigned short* __restrict__ Vt, unsigned short* __restrict__ AO) {
    __shared__ __align__(16) unsigned short Ks[3][64 * 64];  // [t'][d], swizzled
    __shared__ __align__(16) unsigned short Vs[3][64 * 64];  // [d][t'], swizzled
    __shared__ __align__(16) unsigned short U[8][1152];      // per-wave P staging

    const int tid = threadIdx.x;
    const int w = tid >> 6, lane = tid & 63;
    const int quad = lane >> 4, l16 = lane & 15;
    const int bh = blockIdx.x;  // 0..31 fastest: spreads heads across XCDs
    const int y = blockIdx.y;
    const int qb = (y < 8) ? 15 - y : y - 8;  // balanced pairs: (15-y) + y = 15
    const int q0w = qb * 128 + w * 16;        // this wave's 16 q-rows
    const unsigned short* Qh = Qb + (size_t)bh * TT * THS;
    const unsigned short* Kh = Kb + (size_t)bh * TT * THS;
    const unsigned short* Vh = Vt + (size_t)bh * THS * TT;
    const int b = bh >> 4, h = bh & 15;

    bf16x8 aQ[2];
#pragma unroll
    for (int ks = 0; ks < 2; ++ks)
        aQ[ks] = *(const bf16x8*)(
            Qh + (size_t)(q0w + l16) * THS + ks * 32 + quad * 8);

    const float NEGINF = -__builtin_inff();
    const f32x4 vzero = {0.f, 0.f, 0.f, 0.f};
    f32x4 o[4];
    float lp[4];
#pragma unroll
    for (int i = 0; i < 4; i++) { o[i] = vzero; lp[i] = 0.f; }

    const int nkt = 2 * qb + 2;  // 64-key tiles covering [0, qb*128+128); >= 2

    // stage tile kt_ into buffer bf: 512 threads cover 512 16B-chunks in one pass.
    // chunk c: row=c>>3; LDS chunk c&7 holds global chunk (c&7)^(row&7) (G21).
    auto stage = [&](int kt_, int bf) {
        const int c = tid;
        const int row = c >> 3, g = (c & 7) ^ (row & 7);
        gl_lds16(Kh + (size_t)(kt_ * 64 + row) * THS + g * 8, &Ks[bf][c * 8]);
        gl_lds16(Vh + (size_t)row * TT + kt_ * 64 + g * 8, &Vs[bf][c * 8]);
    };

    // ---- prologue: stage tiles 0 and 1; wait only for tile 0 (vmcnt(2)) ----
    stage(0, 0);
    stage(1, 1);
    asm volatile("s_waitcnt vmcnt(2)" ::: "memory");
    __builtin_amdgcn_s_barrier();

    int cur = 0;
    for (int kt = 0; kt < nkt; ++kt) {
        const int t0 = kt * 64;
        const bool st = (kt + 2 < nkt);
        // stage kt+2 into buffer (kt+2)%3 == (cur+2)%3
        if (st) {
            const int bf = (cur >= 1) ? cur - 1 : cur + 2;  // (cur+2)%3
            stage(kt + 2, bf);
        }
        // ---- compute (wave-uniform guard; no barriers inside) ----
        if (t0 <= q0w + 15) {
            const unsigned short* Kc = &Ks[cur][0];
            const unsigned short* Vc = &Vs[cur][0];
            bf16x8 bK[8];
#pragma unroll
            for (int nt = 0; nt < 4; ++nt)
#pragma unroll
                for (int ks = 0; ks < 2; ++ks) {
                    const int row = nt * 16 + l16;
                    bK[nt * 2 + ks] = *(const bf16x8*)(
                        Kc + row * 64 + (((ks * 4 + quad) ^ (row & 7)) * 8));
                }
            const bool needmask = (t0 + 63 > q0w);
            f32x4 s[4];
#pragma unroll
            for (int nt = 0; nt < 4; ++nt) s[nt] = vzero;
            __builtin_amdgcn_s_setprio(1);
#pragma unroll
            for (int ks = 0; ks < 2; ++ks)
#pragma unroll
                for (int nt = 0; nt < 4; ++nt)
                    s[nt] = __builtin_amdgcn_mfma_f32_16x16x32_bf16(
                        aQ[ks], bK[nt * 2 + ks], s[nt], 0, 0, 0);
            __builtin_amdgcn_s_setprio(0);
            unsigned short* Pw = &U[w][0];  // 16 rows x stride 72
#pragma unroll
            for (int r = 0; r < 4; ++r) {
                const int row = q0w + quad * 4 + r;
                float v0 = s[0][r], v1 = s[1][r], v2 = s[2][r], v3 = s[3][r];
                if (needmask) {
                    if (t0 + l16 > row) v0 = NEGINF;
                    if (t0 + 16 + l16 > row) v1 = NEGINF;
                    if (t0 + 32 + l16 > row) v2 = NEGINF;
                    if (t0 + 48 + l16 > row) v3 = NEGINF;
                }
                const float p0 = __builtin_amdgcn_exp2f(v0);
                const float p1 = __builtin_amdgcn_exp2f(v1);
                const float p2 = __builtin_amdgcn_exp2f(v2);
                const float p3 = __builtin_amdgcn_exp2f(v3);
                lp[r] += (p0 + p1) + (p2 + p3);
                const int pr = (quad * 4 + r) * 72;
                Pw[pr + l16] = f2b_hw(p0);
                Pw[pr + 16 + l16] = f2b_hw(p1);
                Pw[pr + 32 + l16] = f2b_hw(p2);
                Pw[pr + 48 + l16] = f2b_hw(p3);
            }
            asm volatile("s_waitcnt lgkmcnt(0)" ::: "memory");  // per-wave P visibility
            bf16x8 aP[2];
            aP[0] = *(const bf16x8*)(Pw + l16 * 72 + quad * 8);
            aP[1] = *(const bf16x8*)(Pw + l16 * 72 + 32 + quad * 8);
            bf16x8 bV[8];
#pragma unroll
            for (int nt = 0; nt < 4; ++nt)
#pragma unroll
                for (int ks = 0; ks < 2; ++ks) {
                    const int row = nt * 16 + l16;
                    bV[nt * 2 + ks] = *(const bf16x8*)(
                        Vc + row * 64 + (((ks * 4 + quad) ^ (row & 7)) * 8));
                }
            __builtin_amdgcn_s_setprio(1);
#pragma unroll
            for (int ks = 0; ks < 2; ++ks)
#pragma unroll
                for (int nt = 0; nt < 4; ++nt)
                    o[nt] = __builtin_amdgcn_mfma_f32_16x16x32_bf16(
                        aP[ks], bV[nt * 2 + ks], o[nt], 0, 0, 0);
            __builtin_amdgcn_s_setprio(0);
        }
        // counted drain: complete all staging issued BEFORE this iteration; this
        // iteration's 2 (if any) stay in flight across the barrier (T4).
        if (st)
            asm volatile("s_waitcnt vmcnt(2)" ::: "memory");
        else
            asm volatile("s_waitcnt vmcnt(0)" ::: "memory");
        __builtin_amdgcn_s_barrier();
        cur = (cur == 2) ? 0 : cur + 1;
    }

    // ---- epilogue: per-wave l reduce + direct scaled AO write (no merge) ----
#pragma unroll
    for (int r = 0; r < 4; ++r) {
        const float L = dpp_sum16(lp[r]);
        const float rcpL = __builtin_amdgcn_rcpf(L);
        const int t = q0w + quad * 4 + r;
        unsigned short* dst = AO + ((size_t)(b * TT + t)) * TC + h * 64;
#pragma unroll
        for (int nt = 0; nt < 4; ++nt)
            dst[nt * 16 + l16] = f2b_hw(o[nt][r] * rcpL);
    }
}

extern "C" void kernel_launch(void* const* d_in, const int* in_sizes, int n_in,
                              void* d_out, int out_size, void* d_ws, size_t ws_size,
                              hipStream_t stream) {
    const float* X = (const float*)d_in[0];      // [2,2048,1024] fp32
    const float* Wqkv = (const float*)d_in[1];   // [1024,3072] fp32
    const float* Wproj = (const float*)d_in[2];  // [1024,1024] fp32
    float* out = (float*)d_out;                  // [2,2048,1024] fp32

    unsigned short* ws = (unsigned short*)d_ws;
    unsigned short* Xb = ws;                           // [4096,1024] bf16
    unsigned short* Wq_t = Xb + 4096 * 1024;           // [3072,1024] bf16
    unsigned short* Wp_t = Wq_t + 3072 * 1024;         // [1024,1024] bf16
    unsigned short* Qb = Wp_t + 1024 * 1024;           // [B,H,T,64] (pre-scaled)
    unsigned short* Kb = Qb + TB * TH * TT * THS;      // [B,H,T,64]
    unsigned short* Vb = Kb + TB * TH * TT * THS;      // [B,H,T,64] (pre-transpose)
    unsigned short* Vt = Vb + TB * TH * TT * THS;      // [B,H,64,T]
    unsigned short* AO = Vt + TB * TH * TT * THS;      // [B,T,C] bf16

    cvt_bf16_k<<<dim3((4096 * 1024) / (8 * 256)), 256, 0, stream>>>(X, Xb);
    transpose_cvt_k<<<dim3(3072 / 32, 1024 / 32), dim3(32, 8), 0, stream>>>(Wqkv, Wq_t, 1024, 3072);
    transpose_cvt_k<<<dim3(1024 / 32, 1024 / 32), dim3(32, 8), 0, stream>>>(Wproj, Wp_t, 1024, 1024);
    gemm_qkv<<<dim3(3072 / 128, 4096 / 128), 256, 0, stream>>>(Xb, Wq_t, 1024, Kb, Qb, Vb);
    vt_k<<<dim3(THS / 32, TT / 32, TB * TH), dim3(32, 8), 0, stream>>>(Vb, Vt);
    attn_k<<<dim3(32, 16), 512, 0, stream>>>(Qb, Kb, Vt, AO);
    gemm_proj<<<dim3(1024 / 64, 4096 / 128), 256, 0, stream>>>(
        AO, Wp_t, 4096, 1024, 1024, out);
}

// Round 17
// 183.108 us; speedup vs baseline: 1.0506x; 1.0318x over previous
//
#include <hip/hip_runtime.h>

// Problem constants: B=2, T=2048, C=1024, H=16, HS=64. fp32 I/O, bf16 internal.
#define TB 2
#define TT 2048
#define TC 1024
#define TH 16
#define THS 64

typedef short bf16x8 __attribute__((ext_vector_type(8)));
typedef float f32x4 __attribute__((ext_vector_type(4)));

// Q pre-scale: (1/sqrt(C)) * log2(e), folded into Qb at QKV-GEMM epilogue
#define QSCALE 0.0450842200278f

// round-to-nearest-even fp32 -> bf16 bit pattern (manual; used in cold kernels)
__device__ inline unsigned short f2b(float f) {
    unsigned u = __builtin_bit_cast(unsigned, f);
    unsigned r = (u + 0x7fffu + ((u >> 16) & 1u)) >> 16;
    return (unsigned short)r;
}
// native RNE fp32->bf16 via compiler fptrunc (lowers to HW cvt on gfx950).
__device__ inline unsigned short f2b_hw(float f) {
    __bf16 h = (__bf16)f;
    return __builtin_bit_cast(unsigned short, h);
}
__device__ inline float b2f(unsigned short h) {
    unsigned u = ((unsigned)h) << 16;
    return __builtin_bit_cast(float, u);
}

// async global->LDS 16B/lane. LDS dest contract: wave-uniform base + lane*16.
__device__ inline void gl_lds16(const unsigned short* g, unsigned short* l) {
    __builtin_amdgcn_global_load_lds(
        (const __attribute__((address_space(1))) unsigned int*)(g),
        (__attribute__((address_space(3))) unsigned int*)(l), 16, 0, 0);
}

// 16-lane all-reduce sum via DPP row_ror butterfly (once per row at kernel end)
__device__ inline float dpp_sum16(float x) {
    int t;
    t = __builtin_amdgcn_update_dpp(0, __builtin_bit_cast(int, x), 0x128, 0xf, 0xf, true);
    x += __builtin_bit_cast(float, t);
    t = __builtin_amdgcn_update_dpp(0, __builtin_bit_cast(int, x), 0x124, 0xf, 0xf, true);
    x += __builtin_bit_cast(float, t);
    t = __builtin_amdgcn_update_dpp(0, __builtin_bit_cast(int, x), 0x122, 0xf, 0xf, true);
    x += __builtin_bit_cast(float, t);
    t = __builtin_amdgcn_update_dpp(0, __builtin_bit_cast(int, x), 0x121, 0xf, 0xf, true);
    x += __builtin_bit_cast(float, t);
    return x;
}

// ---------------- convert fp32 -> bf16, 8 elements/thread ----------------
__global__ void cvt_bf16_k(const float* __restrict__ in, unsigned short* __restrict__ out) {
    const int i = blockIdx.x * blockDim.x + threadIdx.x;
    const float4* p = (const float4*)in + (size_t)i * 2;
    const float4 a = p[0], b = p[1];
    bf16x8 v;
    v[0] = (short)f2b(a.x); v[1] = (short)f2b(a.y);
    v[2] = (short)f2b(a.z); v[3] = (short)f2b(a.w);
    v[4] = (short)f2b(b.x); v[5] = (short)f2b(b.y);
    v[6] = (short)f2b(b.z); v[7] = (short)f2b(b.w);
    *(bf16x8*)(out + (size_t)i * 8) = v;
}

// ------------- transpose + convert: fp32 in[R][Cc] -> bf16 out[Cc][R] -------------
__global__ void transpose_cvt_k(const float* __restrict__ in,
                                unsigned short* __restrict__ out, int R, int Cc) {
    __shared__ float tile[32][33];
    const int tx = threadIdx.x, ty = threadIdx.y;
    const int r0 = blockIdx.y * 32, c0 = blockIdx.x * 32;
#pragma unroll
    for (int i = 0; i < 4; i++)
        tile[ty + i * 8][tx] = in[(size_t)(r0 + ty + i * 8) * Cc + c0 + tx];
    __syncthreads();
#pragma unroll
    for (int i = 0; i < 4; i++)
        out[(size_t)(c0 + ty + i * 8) * R + r0 + tx] = f2b(tile[tx][ty + i * 8]);
}

// ------- QKV GEMM: C = Xb * Wq_t^T, scatter epilogue -> K/Q [B,H,T,64] and
// V DIRECTLY TRANSPOSED -> Vt [B,H,64,T] (R17: vt_k deleted; the V quadrant's
// d-range is exactly [0,64) because cw=n0+wn is 64-aligned, so the register
// tile can be written [d][t] with pure address arithmetic; stores are
// fire-and-forget and each 64B line is fully covered within the block).
// 3-buffer counted-vmcnt pipeline (R15) + hoisted scalar epilogue + XCD swizzle
// (R14) + T5 setprio on the MFMA cluster (R16: helped GEMMs).
__global__ __launch_bounds__(256) void gemm_qkv(
    const unsigned short* __restrict__ A, const unsigned short* __restrict__ Bt, int K,
    unsigned short* __restrict__ outK, unsigned short* __restrict__ outQ,
    unsigned short* __restrict__ outVt) {
    __shared__ __align__(16) unsigned short As[3][128 * 32];
    __shared__ __align__(16) unsigned short Bs[3][128 * 32];

    const int tid = threadIdx.x;
    const int wave = tid >> 6, lane = tid & 63;
    const int quad = lane >> 4, l16 = lane & 15;
    const int wm = (wave >> 1) * 64, wn = (wave & 1) * 64;
    const int hwid = blockIdx.y * 24 + blockIdx.x;
    const int swid = (hwid & 7) * 96 + (hwid >> 3);
    const int m0 = (swid / 24) * 128, n0 = (swid % 24) * 128;

    const f32x4 vzero = {0.f, 0.f, 0.f, 0.f};
    f32x4 acc[4][4];
#pragma unroll
    for (int i = 0; i < 4; i++)
#pragma unroll
        for (int j = 0; j < 4; j++) acc[i][j] = vzero;

    const int nk = K >> 5;  // 32

    auto stage = [&](int kt_, int bf) {
#pragma unroll
        for (int it = 0; it < 2; ++it) {
            const int chunk = tid + it * 256;
            const int r = chunk >> 2, col = (chunk & 3) * 8;
            gl_lds16(A + (size_t)(m0 + r) * K + kt_ * 32 + col, &As[bf][chunk * 8]);
            gl_lds16(Bt + (size_t)(n0 + r) * K + kt_ * 32 + col, &Bs[bf][chunk * 8]);
        }
    };

    stage(0, 0);
    stage(1, 1);
    asm volatile("s_waitcnt vmcnt(4)" ::: "memory");
    __builtin_amdgcn_s_barrier();

    int cur = 0;
    for (int kt = 0; kt < nk; ++kt) {
        const bool st = (kt + 2 < nk);
        if (st) {
            const int bf = (cur >= 1) ? cur - 1 : cur + 2;  // (cur+2)%3
            stage(kt + 2, bf);
        }
        bf16x8 af[4], bfr[4];
#pragma unroll
        for (int f = 0; f < 4; ++f) {
            af[f] = *(const bf16x8*)(&As[cur][(wm + f * 16 + l16) * 32 + quad * 8]);
            bfr[f] = *(const bf16x8*)(&Bs[cur][(wn + f * 16 + l16) * 32 + quad * 8]);
        }
        __builtin_amdgcn_s_setprio(1);
#pragma unroll
        for (int fm = 0; fm < 4; ++fm)
#pragma unroll
            for (int fn = 0; fn < 4; ++fn)
                acc[fm][fn] = __builtin_amdgcn_mfma_f32_16x16x32_bf16(
                    af[fm], bfr[fn], acc[fm][fn], 0, 0, 0);
        __builtin_amdgcn_s_setprio(0);
        if (st)
            asm volatile("s_waitcnt vmcnt(4)" ::: "memory");
        else
            asm volatile("s_waitcnt vmcnt(0)" ::: "memory");
        __builtin_amdgcn_s_barrier();
        cur = (cur == 2) ? 0 : cur + 1;
    }

    // ---- epilogue (C/D layout col=lane&15, row=quad*4+reg), hoisted scalar form.
    {
        const int cw = n0 + wn;
        const int chunkc = cw >> 10;            // 0:K 1:Q 2:V (module split order)
        const int hh = (cw & (TC - 1)) >> 6;
        const int rw = m0 + wm;
        const int b = rw >> 11;
        const int tbase = rw & (TT - 1);
        if (chunkc == 2) {
            // direct transposed V write: Vt[bh][d][t], d = fn*16+l16,
            // t = tbase + fm*16 + quad*4 + r
            unsigned short* baseV =
                outVt + (size_t)(b * TH + hh) * THS * TT + tbase;
#pragma unroll
            for (int fn = 0; fn < 4; ++fn) {
                unsigned short* dcol = baseV + (size_t)(fn * 16 + l16) * TT;
#pragma unroll
                for (int fm = 0; fm < 4; ++fm)
#pragma unroll
                    for (int r = 0; r < 4; ++r)
                        dcol[fm * 16 + quad * 4 + r] = f2b_hw(acc[fm][fn][r]);
            }
        } else {
            unsigned short* outp = (chunkc == 0) ? outK : outQ;
            const float scale = (chunkc == 1) ? QSCALE : 1.0f;
            unsigned short* base =
                outp + ((size_t)((b * TH + hh) * TT + tbase)) * THS + l16;
#pragma unroll
            for (int fm = 0; fm < 4; ++fm) {
#pragma unroll
                for (int r = 0; r < 4; ++r) {
                    unsigned short* rowp = base + (fm * 16 + quad * 4 + r) * THS;
#pragma unroll
                    for (int fn = 0; fn < 4; ++fn)
                        rowp[fn * 16] = f2b_hw(acc[fm][fn][r] * scale);
                }
            }
        }
    }
}

// ------- proj GEMM: out[M,N] = A[M,K] * Bt[N,K]^T, 128x64 tile, fp32 out ---------
// 3-buffer counted-vmcnt pipeline (R15) + T5 setprio (R16).
__global__ __launch_bounds__(256) void gemm_proj(
    const unsigned short* __restrict__ A, const unsigned short* __restrict__ Bt,
    int M, int N, int K, float* __restrict__ outF) {
    __shared__ __align__(16) unsigned short As[3][128 * 32];
    __shared__ __align__(16) unsigned short Bs[3][64 * 32];

    const int tid = threadIdx.x;
    const int wave = tid >> 6, lane = tid & 63;
    const int quad = lane >> 4, l16 = lane & 15;
    const int wm = wave * 32;
    const int m0 = blockIdx.y * 128, n0 = blockIdx.x * 64;

    const f32x4 vzero = {0.f, 0.f, 0.f, 0.f};
    f32x4 acc[2][4];
#pragma unroll
    for (int i = 0; i < 2; i++)
#pragma unroll
        for (int j = 0; j < 4; j++) acc[i][j] = vzero;

    const int nk = K >> 5;  // 32

    auto stage = [&](int kt_, int bf) {
#pragma unroll
        for (int it = 0; it < 2; ++it) {
            const int chunk = tid + it * 256;
            const int r = chunk >> 2, col = (chunk & 3) * 8;
            gl_lds16(A + (size_t)(m0 + r) * K + kt_ * 32 + col, &As[bf][chunk * 8]);
        }
        {
            const int r = tid >> 2, col = (tid & 3) * 8;
            gl_lds16(Bt + (size_t)(n0 + r) * K + kt_ * 32 + col, &Bs[bf][tid * 8]);
        }
    };

    stage(0, 0);
    stage(1, 1);
    asm volatile("s_waitcnt vmcnt(3)" ::: "memory");
    __builtin_amdgcn_s_barrier();

    int cur = 0;
    for (int kt = 0; kt < nk; ++kt) {
        const bool st = (kt + 2 < nk);
        if (st) {
            const int bf = (cur >= 1) ? cur - 1 : cur + 2;  // (cur+2)%3
            stage(kt + 2, bf);
        }
        bf16x8 af[2], bfr[4];
#pragma unroll
        for (int f = 0; f < 2; ++f)
            af[f] = *(const bf16x8*)(&As[cur][(wm + f * 16 + l16) * 32 + quad * 8]);
#pragma unroll
        for (int f = 0; f < 4; ++f)
            bfr[f] = *(const bf16x8*)(&Bs[cur][(f * 16 + l16) * 32 + quad * 8]);
        __builtin_amdgcn_s_setprio(1);
#pragma unroll
        for (int fm = 0; fm < 2; ++fm)
#pragma unroll
            for (int fn = 0; fn < 4; ++fn)
                acc[fm][fn] = __builtin_amdgcn_mfma_f32_16x16x32_bf16(
                    af[fm], bfr[fn], acc[fm][fn], 0, 0, 0);
        __builtin_amdgcn_s_setprio(0);
        if (st)
            asm volatile("s_waitcnt vmcnt(3)" ::: "memory");
        else
            asm volatile("s_waitcnt vmcnt(0)" ::: "memory");
        __builtin_amdgcn_s_barrier();
        cur = (cur == 2) ? 0 : cur + 1;
    }

#pragma unroll
    for (int fm = 0; fm < 2; ++fm)
#pragma unroll
        for (int fn = 0; fn < 4; ++fn)
#pragma unroll
            for (int r = 0; r < 4; ++r) {
                const int row = m0 + wm + fm * 16 + quad * 4 + r;
                const int col = n0 + fn * 16 + l16;
                outF[(size_t)row * N + col] = acc[fm][fn][r];
            }
}

// ---- flash attention v4: 8 waves x 16 q-rows, LDS K/V, counted-vmcnt pipeline ----
// Best verified config (R8/R13-R15: attn ~48.8-49us). setprio REVERTED (R16
// measured it -1.5us on attn; barrier-synced waves within the block gave the
// scheduler nothing useful to arbitrate).
__global__ __launch_bounds__(512) void attn_k(
    const unsigned short* __restrict__ Qb, const unsigned short* __restrict__ Kb,
    const unsigned short* __restrict__ Vt, unsigned short* __restrict__ AO) {
    __shared__ __align__(16) unsigned short Ks[3][64 * 64];  // [t'][d], swizzled
    __shared__ __align__(16) unsigned short Vs[3][64 * 64];  // [d][t'], swizzled
    __shared__ __align__(16) unsigned short U[8][1152];      // per-wave P staging

    const int tid = threadIdx.x;
    const int w = tid >> 6, lane = tid & 63;
    const int quad = lane >> 4, l16 = lane & 15;
    const int bh = blockIdx.x;  // 0..31 fastest: spreads heads across XCDs
    const int y = blockIdx.y;
    const int qb = (y < 8) ? 15 - y : y - 8;  // balanced pairs: (15-y) + y = 15
    const int q0w = qb * 128 + w * 16;        // this wave's 16 q-rows
    const unsigned short* Qh = Qb + (size_t)bh * TT * THS;
    const unsigned short* Kh = Kb + (size_t)bh * TT * THS;
    const unsigned short* Vh = Vt + (size_t)bh * THS * TT;
    const int b = bh >> 4, h = bh & 15;

    bf16x8 aQ[2];
#pragma unroll
    for (int ks = 0; ks < 2; ++ks)
        aQ[ks] = *(const bf16x8*)(
            Qh + (size_t)(q0w + l16) * THS + ks * 32 + quad * 8);

    const float NEGINF = -__builtin_inff();
    const f32x4 vzero = {0.f, 0.f, 0.f, 0.f};
    f32x4 o[4];
    float lp[4];
#pragma unroll
    for (int i = 0; i < 4; i++) { o[i] = vzero; lp[i] = 0.f; }

    const int nkt = 2 * qb + 2;  // 64-key tiles covering [0, qb*128+128); >= 2

    // stage tile kt_ into buffer bf: 512 threads cover 512 16B-chunks in one pass.
    // chunk c: row=c>>3; LDS chunk c&7 holds global chunk (c&7)^(row&7) (G21).
    auto stage = [&](int kt_, int bf) {
        const int c = tid;
        const int row = c >> 3, g = (c & 7) ^ (row & 7);
        gl_lds16(Kh + (size_t)(kt_ * 64 + row) * THS + g * 8, &Ks[bf][c * 8]);
        gl_lds16(Vh + (size_t)row * TT + kt_ * 64 + g * 8, &Vs[bf][c * 8]);
    };

    // ---- prologue: stage tiles 0 and 1; wait only for tile 0 (vmcnt(2)) ----
    stage(0, 0);
    stage(1, 1);
    asm volatile("s_waitcnt vmcnt(2)" ::: "memory");
    __builtin_amdgcn_s_barrier();

    int cur = 0;
    for (int kt = 0; kt < nkt; ++kt) {
        const int t0 = kt * 64;
        const bool st = (kt + 2 < nkt);
        // stage kt+2 into buffer (kt+2)%3 == (cur+2)%3
        if (st) {
            const int bf = (cur >= 1) ? cur - 1 : cur + 2;  // (cur+2)%3
            stage(kt + 2, bf);
        }
        // ---- compute (wave-uniform guard; no barriers inside) ----
        if (t0 <= q0w + 15) {
            const unsigned short* Kc = &Ks[cur][0];
            const unsigned short* Vc = &Vs[cur][0];
            bf16x8 bK[8];
#pragma unroll
            for (int nt = 0; nt < 4; ++nt)
#pragma unroll
                for (int ks = 0; ks < 2; ++ks) {
                    const int row = nt * 16 + l16;
                    bK[nt * 2 + ks] = *(const bf16x8*)(
                        Kc + row * 64 + (((ks * 4 + quad) ^ (row & 7)) * 8));
                }
            const bool needmask = (t0 + 63 > q0w);
            f32x4 s[4];
#pragma unroll
            for (int nt = 0; nt < 4; ++nt) s[nt] = vzero;
#pragma unroll
            for (int ks = 0; ks < 2; ++ks)
#pragma unroll
                for (int nt = 0; nt < 4; ++nt)
                    s[nt] = __builtin_amdgcn_mfma_f32_16x16x32_bf16(
                        aQ[ks], bK[nt * 2 + ks], s[nt], 0, 0, 0);
            unsigned short* Pw = &U[w][0];  // 16 rows x stride 72
#pragma unroll
            for (int r = 0; r < 4; ++r) {
                const int row = q0w + quad * 4 + r;
                float v0 = s[0][r], v1 = s[1][r], v2 = s[2][r], v3 = s[3][r];
                if (needmask) {
                    if (t0 + l16 > row) v0 = NEGINF;
                    if (t0 + 16 + l16 > row) v1 = NEGINF;
                    if (t0 + 32 + l16 > row) v2 = NEGINF;
                    if (t0 + 48 + l16 > row) v3 = NEGINF;
                }
                const float p0 = __builtin_amdgcn_exp2f(v0);
                const float p1 = __builtin_amdgcn_exp2f(v1);
                const float p2 = __builtin_amdgcn_exp2f(v2);
                const float p3 = __builtin_amdgcn_exp2f(v3);
                lp[r] += (p0 + p1) + (p2 + p3);
                const int pr = (quad * 4 + r) * 72;
                Pw[pr + l16] = f2b_hw(p0);
                Pw[pr + 16 + l16] = f2b_hw(p1);
                Pw[pr + 32 + l16] = f2b_hw(p2);
                Pw[pr + 48 + l16] = f2b_hw(p3);
            }
            asm volatile("s_waitcnt lgkmcnt(0)" ::: "memory");  // per-wave P visibility
            bf16x8 aP[2];
            aP[0] = *(const bf16x8*)(Pw + l16 * 72 + quad * 8);
            aP[1] = *(const bf16x8*)(Pw + l16 * 72 + 32 + quad * 8);
            bf16x8 bV[8];
#pragma unroll
            for (int nt = 0; nt < 4; ++nt)
#pragma unroll
                for (int ks = 0; ks < 2; ++ks) {
                    const int row = nt * 16 + l16;
                    bV[nt * 2 + ks] = *(const bf16x8*)(
                        Vc + row * 64 + (((ks * 4 + quad) ^ (row & 7)) * 8));
                }
#pragma unroll
            for (int ks = 0; ks < 2; ++ks)
#pragma unroll
                for (int nt = 0; nt < 4; ++nt)
                    o[nt] = __builtin_amdgcn_mfma_f32_16x16x32_bf16(
                        aP[ks], bV[nt * 2 + ks], o[nt], 0, 0, 0);
        }
        // counted drain: complete all staging issued BEFORE this iteration; this
        // iteration's 2 (if any) stay in flight across the barrier (T4).
        if (st)
            asm volatile("s_waitcnt vmcnt(2)" ::: "memory");
        else
            asm volatile("s_waitcnt vmcnt(0)" ::: "memory");
        __builtin_amdgcn_s_barrier();
        cur = (cur == 2) ? 0 : cur + 1;
    }

    // ---- epilogue: per-wave l reduce + direct scaled AO write (no merge) ----
#pragma unroll
    for (int r = 0; r < 4; ++r) {
        const float L = dpp_sum16(lp[r]);
        const float rcpL = __builtin_amdgcn_rcpf(L);
        const int t = q0w + quad * 4 + r;
        unsigned short* dst = AO + ((size_t)(b * TT + t)) * TC + h * 64;
#pragma unroll
        for (int nt = 0; nt < 4; ++nt)
            dst[nt * 16 + l16] = f2b_hw(o[nt][r] * rcpL);
    }
}

extern "C" void kernel_launch(void* const* d_in, const int* in_sizes, int n_in,
                              void* d_out, int out_size, void* d_ws, size_t ws_size,
                              hipStream_t stream) {
    const float* X = (const float*)d_in[0];      // [2,2048,1024] fp32
    const float* Wqkv = (const float*)d_in[1];   // [1024,3072] fp32
    const float* Wproj = (const float*)d_in[2];  // [1024,1024] fp32
    float* out = (float*)d_out;                  // [2,2048,1024] fp32

    unsigned short* ws = (unsigned short*)d_ws;
    unsigned short* Xb = ws;                           // [4096,1024] bf16
    unsigned short* Wq_t = Xb + 4096 * 1024;           // [3072,1024] bf16
    unsigned short* Wp_t = Wq_t + 3072 * 1024;         // [1024,1024] bf16
    unsigned short* Qb = Wp_t + 1024 * 1024;           // [B,H,T,64] (pre-scaled)
    unsigned short* Kb = Qb + TB * TH * TT * THS;      // [B,H,T,64]
    unsigned short* Vt = Kb + TB * TH * TT * THS;      // [B,H,64,T] (written direct)
    unsigned short* AO = Vt + TB * TH * TT * THS;      // [B,T,C] bf16

    cvt_bf16_k<<<dim3((4096 * 1024) / (8 * 256)), 256, 0, stream>>>(X, Xb);
    transpose_cvt_k<<<dim3(3072 / 32, 1024 / 32), dim3(32, 8), 0, stream>>>(Wqkv, Wq_t, 1024, 3072);
    transpose_cvt_k<<<dim3(1024 / 32, 1024 / 32), dim3(32, 8), 0, stream>>>(Wproj, Wp_t, 1024, 1024);
    gemm_qkv<<<dim3(3072 / 128, 4096 / 128), 256, 0, stream>>>(Xb, Wq_t, 1024, Kb, Qb, Vt);
    attn_k<<<dim3(32, 16), 512, 0, stream>>>(Qb, Kb, Vt, AO);
    gemm_proj<<<dim3(1024 / 64, 4096 / 128), 256, 0, stream>>>(
        AO, Wp_t, 4096, 1024, 1024, out);
}